// Round 10
// baseline (416.201 us; speedup 1.0000x reference)
//
#include <hip/hip_runtime.h>
#include <math.h>

// Problem constants (match reference)
#define NP 10000
#define NB 30000
#define NEDGE 300000
#define BEDGE 8192
#define EAD 16
#define HID 64
#define GH 4
#define CW 256      // GH*HID
#define DD 128
#define SEQ 6
#define NCLS 10
#define L 2
#define NEACOL 64   // ea-colsum blocks folded into gat2 grid

#if defined(__has_builtin)
#  if __has_builtin(__builtin_amdgcn_fdot2)
#    define HAVE_DOT2 1
#  else
#    define HAVE_DOT2 0
#  endif
#else
#  define HAVE_DOT2 0
#endif

typedef _Float16 h16x2 __attribute__((ext_vector_type(2)));

__device__ __forceinline__ float geluf(float x){
  // jax.nn.gelu(approximate=False)
  return 0.5f * x * (1.0f + erff(x * 0.7071067811865475f));
}

__device__ __forceinline__ float b2f(unsigned short u){
  unsigned v = ((unsigned)u) << 16;
  return __int_as_float(v);
}
__device__ __forceinline__ unsigned short f2b(float f){
  unsigned x = __float_as_uint(f);
  unsigned r = x + 0x7FFF + ((x >> 16) & 1);   // round-to-nearest-even
  return (unsigned short)(r >> 16);
}

typedef __attribute__((ext_vector_type(8))) short bf16x8;
typedef __attribute__((ext_vector_type(4))) float f32x4;

// ---------------------------------------------------------------------------
// MFMA GEMM body: out_bf16[M][N] = (GELU?)(A[M][KQ] @ W[KQ][N] + bias[N])
// Epilogue routes the C tile through LDS (reusing sWt after a barrier) so
// global stores are coalesced int4 (16B/lane) instead of scalar ushort.
// ---------------------------------------------------------------------------
template<int KQ, int NTILES, bool A_F32, bool GELU>
__device__ __forceinline__
void mfma_gemm_body(int bid, const void* __restrict__ Av, const float* __restrict__ W,
                    const float* __restrict__ bias, unsigned short* __restrict__ out,
                    int M, unsigned short* __restrict__ sWt)
{
  constexpr int N  = NTILES * 16;
  constexpr int KP = KQ + 8;
  constexpr int NP8 = N + 8;     // padded LDS row stride (ushorts), 16B-aligned
  int t = threadIdx.x, w = t >> 6, l = t & 63;
  int c = l & 15, g = l >> 4;
  for (int idx = t; idx < KQ*N; idx += 256){
    int k = idx / N, n = idx - k*N;
    sWt[n*KP + k] = f2b(W[idx]);
  }
  __syncthreads();
  int rowbase = bid*64 + w*16;
  int arow = rowbase + c; if (arow > M-1) arow = M-1;   // clamp (no OOB reads)
  f32x4 acc[NTILES] = {};
  #pragma unroll
  for (int ks = 0; ks < KQ/32; ++ks){
    int koff = ks*32 + g*8;
    bf16x8 a;
    if constexpr (A_F32){
      const float* Af = (const float*)Av + (size_t)arow*KQ + koff;
      float4 f0 = *(const float4*)Af;
      float4 f1 = *(const float4*)(Af + 4);
      a[0]=(short)f2b(f0.x); a[1]=(short)f2b(f0.y); a[2]=(short)f2b(f0.z); a[3]=(short)f2b(f0.w);
      a[4]=(short)f2b(f1.x); a[5]=(short)f2b(f1.y); a[6]=(short)f2b(f1.z); a[7]=(short)f2b(f1.w);
    } else {
      a = *(const bf16x8*)((const unsigned short*)Av + (size_t)arow*KQ + koff);
    }
    #pragma unroll
    for (int nt = 0; nt < NTILES; ++nt){
      bf16x8 b = *(const bf16x8*)&sWt[(nt*16 + c)*KP + koff];
      acc[nt] = __builtin_amdgcn_mfma_f32_16x16x32_bf16(a, b, acc[nt], 0, 0, 0);
    }
  }
  // epilogue: acc -> LDS (bias/gelu/bf16), then coalesced 16B global stores
  __syncthreads();     // all waves done reading sWt
  #pragma unroll
  for (int nt = 0; nt < NTILES; ++nt){
    #pragma unroll
    for (int j = 0; j < 4; ++j){
      float v = acc[nt][j] + bias[nt*16 + c];
      if (GELU) v = geluf(v);
      sWt[(w*16 + g*4 + j)*NP8 + nt*16 + c] = f2b(v);
    }
  }
  __syncthreads();
  int blockrow0 = bid*64;
  constexpr int C8 = N/8;        // 16B chunks per row
  for (int idx = t; idx < 64*C8; idx += 256){
    int row = idx / C8, c8 = idx - row*C8;
    if (blockrow0 + row < M){
      *(int4*)(out + (size_t)(blockrow0 + row)*N + c8*8) =
          *(const int4*)&sWt[row*NP8 + c8*8];
    }
  }
}

// ---------------------------------------------------------------------------
// k1: edge-degree count (both dirs) || node encoders (pitcher+batter) merged.
// ---------------------------------------------------------------------------
__global__ __launch_bounds__(256)
void k1_count_enc(const int* __restrict__ edst, const int* __restrict__ esrc,
                  int* __restrict__ degA, int* __restrict__ degB,
                  const float* __restrict__ pit, const float* __restrict__ Wp,
                  const float* __restrict__ bp, unsigned short* __restrict__ px,
                  const float* __restrict__ bat, const float* __restrict__ Wb,
                  const float* __restrict__ bb, unsigned short* __restrict__ bx,
                  int nbCount, int nbP)
{
  __shared__ unsigned short sWt[64*136];   // N=64, KP=136 (>= 64*72 for epilogue)
  int b = blockIdx.x;
  if (b < nbCount){
    int i = b*256 + threadIdx.x;
    if (i < NEDGE){
      atomicAdd(&degA[edst[i]], 1);
      atomicAdd(&degB[esrc[i]], 1);
    }
  } else if (b < nbCount + nbP){
    mfma_gemm_body<128,4,true,true>(b - nbCount, pit, Wp, bp, px, NP, sWt);
  } else {
    mfma_gemm_body<128,4,true,true>(b - nbCount - nbP, bat, Wb, bb, bx, NB, sWt);
  }
}

// ---------------------------------------------------------------------------
// scan: shuffle-based exclusive scan, 4 elems/thread
// ---------------------------------------------------------------------------
__device__ void scan_dev(const int* __restrict__ deg, int* __restrict__ row_start,
                         int* __restrict__ cursor, int n){
  __shared__ int wsum[16];
  __shared__ int sbase;
  int t = threadIdx.x, w = t >> 6, l = t & 63;
  if (t == 0) sbase = 0;
  __syncthreads();
  for (int base = 0; base < n; base += 4096){
    int i = base + t*4;
    int4 v = make_int4(0,0,0,0);
    if (i < n) v = *(const int4*)(deg + i);
    int tsum = v.x + v.y + v.z + v.w;
    int x = tsum;
    #pragma unroll
    for (int off = 1; off < 64; off <<= 1){
      int y = __shfl_up(x, off);
      if (l >= off) x += y;
    }
    if (l == 63) wsum[w] = x;
    __syncthreads();
    int woff = 0, tot = 0;
    #pragma unroll
    for (int ww = 0; ww < 16; ++ww){
      int wv = wsum[ww];
      if (ww < w) woff += wv;
      tot += wv;
    }
    int excl = sbase + woff + x - tsum;
    if (i < n){
      int e1 = excl + v.x, e2 = excl + v.x + v.y, e3 = excl + v.x + v.y + v.z;
      row_start[i]   = excl; cursor[i]   = excl;
      row_start[i+1] = e1;   cursor[i+1] = e1;
      row_start[i+2] = e2;   cursor[i+2] = e2;
      row_start[i+3] = e3;   cursor[i+3] = e3;
    }
    __syncthreads();
    if (t == 0) sbase += tot;
    __syncthreads();
  }
  if (t == 0) row_start[n] = sbase;
}

__global__ __launch_bounds__(1024)
void scan2_kernel(const int* __restrict__ degA, int* __restrict__ rsA, int* __restrict__ curA, int nA,
                  const int* __restrict__ degB, int* __restrict__ rsB, int* __restrict__ curB, int nB,
                  float* __restrict__ mvec){
  if (blockIdx.x == 0){
    scan_dev(degA, rsA, curA, nA);
  } else {
    if (threadIdx.x < 144) mvec[threadIdx.x] = 0.f;   // zero mvec for colsum atomics
    scan_dev(degB, rsB, curB, nB);
  }
}

// ---------------------------------------------------------------------------
// k2: CSR scatter (both dirs) || all 4 GAT projection GEMMs merged.
// ---------------------------------------------------------------------------
__global__ __launch_bounds__(256)
void k2_scatter_proj(const int* __restrict__ edst, const int* __restrict__ esrc,
                     int* __restrict__ curA, int* __restrict__ curB,
                     int2* __restrict__ csrA, int2* __restrict__ csrB,
                     const unsigned short* __restrict__ px, const unsigned short* __restrict__ bx,
                     const float* __restrict__ rel_Wl, const float* __restrict__ rel_bl,
                     const float* __restrict__ rel_Wr, const float* __restrict__ rel_br,
                     const float* __restrict__ rev_Wl, const float* __restrict__ rev_bl,
                     const float* __restrict__ rev_Wr, const float* __restrict__ rev_br,
                     unsigned short* __restrict__ xlA, unsigned short* __restrict__ xrA,
                     unsigned short* __restrict__ xlB, unsigned short* __restrict__ xrB,
                     int nbScat, int nbP, int nbB)
{
  __shared__ unsigned short sWt[256*72];   // N=256, KP=72 (>= 64*264 for epilogue)
  int b = blockIdx.x;
  if (b < nbScat){
    int i = b*256 + threadIdx.x;
    if (i < NEDGE){
      int d = edst[i], s = esrc[i];
      int p = atomicAdd(&curA[d], 1);
      csrA[p] = make_int2(i, s);
      int q = atomicAdd(&curB[s], 1);
      csrB[q] = make_int2(i, d);
    }
  } else {
    b -= nbScat;
    if (b < nbP)               mfma_gemm_body<64,16,false,false>(b,            px, rel_Wl, rel_bl, xlA, NP, sWt);
    else if (b < nbP + nbB)    mfma_gemm_body<64,16,false,false>(b-nbP,        bx, rel_Wr, rel_br, xrA, NB, sWt);
    else if (b < nbP + 2*nbB)  mfma_gemm_body<64,16,false,false>(b-nbP-nbB,    bx, rev_Wl, rev_bl, xlB, NB, sWt);
    else                       mfma_gemm_body<64,16,false,false>(b-nbP-2*nbB,  px, rev_Wr, rev_br, xrB, NP, sWt);
  }
}

// ---------------------------------------------------------------------------
// Vectorized column-mean segment (used for ea inside gat2 grid).
// ---------------------------------------------------------------------------
__device__ __forceinline__ void colsum_seg(int bid, int nb, const float4* __restrict__ in4,
                                           long total4, int n4, float* __restrict__ out,
                                           float scale, float* lds){
  int t = threadIdx.x, l = t & 63, w = t >> 6;
  long gid = (long)bid*256 + t;
  long stride = (long)nb*256;
  float4 acc = make_float4(0.f,0.f,0.f,0.f);
  for (long i = gid; i < total4; i += stride){
    float4 v = in4[i];
    acc.x += v.x; acc.y += v.y; acc.z += v.z; acc.w += v.w;
  }
  for (int off = n4; off < 64; off <<= 1){
    acc.x += __shfl_xor(acc.x, off);
    acc.y += __shfl_xor(acc.y, off);
    acc.z += __shfl_xor(acc.z, off);
    acc.w += __shfl_xor(acc.w, off);
  }
  if (l < n4) *(float4*)&lds[(w*n4 + l)*4] = acc;
  __syncthreads();
  if (t < n4*4){
    float sum = lds[t] + lds[n4*4 + t] + lds[2*n4*4 + t] + lds[3*n4*4 + t];
    atomicAdd(&out[t], sum * scale);
  }
  __syncthreads();
}

// ---------------------------------------------------------------------------
// GAT pair-compute (R5-verified math, no online-max). DOT2 / f32 fallback.
// DOT2 path reads the per-lane We columns from REGISTERS (wreg[8], hoisted
// once after staging): loop-invariant, 32 VGPRs. If the allocator refuses,
// worst case it re-reads LDS (status quo).
// ---------------------------------------------------------------------------
#if HAVE_DOT2
typedef int evt_t;
__device__ __forceinline__ int evload(const float* __restrict__ ea, int e, int l){
  float2 fv = *(const float2*)(ea + (size_t)e*EAD + 2*(l & 7));
  return __builtin_bit_cast(int, __builtin_amdgcn_cvt_pkrtz(fv.x, fv.y));
}
#define GAT_PAIR(X0, X1, EV0, EV1, V1OK, P0MASK)                             \
  {                                                                          \
    float x0 = b2f(X0.x), x1 = b2f(X0.y), x2 = b2f(X0.z), x3 = b2f(X0.w);    \
    float y0 = b2f(X1.x), y1 = b2f(X1.y), y2 = b2f(X1.z), y3 = b2f(X1.w);    \
    float h00 = x0 + r0, h01 = x1 + r1, h02 = x2 + r2, h03 = x3 + r3;        \
    float h10 = y0 + r0, h11 = y1 + r1, h12 = y2 + r2, h13 = y3 + r3;        \
    _Pragma("unroll")                                                        \
    for (int j = 0; j < 8; ++j){                                             \
      int c0 = __builtin_amdgcn_readlane(EV0, j);                            \
      int c1 = __builtin_amdgcn_readlane(EV1, j);                            \
      h16x2 e0 = __builtin_bit_cast(h16x2, c0);                              \
      h16x2 e1 = __builtin_bit_cast(h16x2, c1);                              \
      int4 wr = wreg[j];                                                     \
      h16x2 w0 = __builtin_bit_cast(h16x2, wr.x);                            \
      h16x2 w1 = __builtin_bit_cast(h16x2, wr.y);                            \
      h16x2 w2 = __builtin_bit_cast(h16x2, wr.z);                            \
      h16x2 w3 = __builtin_bit_cast(h16x2, wr.w);                            \
      h00 = __builtin_amdgcn_fdot2(e0, w0, h00, false);                      \
      h01 = __builtin_amdgcn_fdot2(e0, w1, h01, false);                      \
      h02 = __builtin_amdgcn_fdot2(e0, w2, h02, false);                      \
      h03 = __builtin_amdgcn_fdot2(e0, w3, h03, false);                      \
      h10 = __builtin_amdgcn_fdot2(e1, w0, h10, false);                      \
      h11 = __builtin_amdgcn_fdot2(e1, w1, h11, false);                      \
      h12 = __builtin_amdgcn_fdot2(e1, w2, h12, false);                      \
      h13 = __builtin_amdgcn_fdot2(e1, w3, h13, false);                      \
    }                                                                        \
    h00 = fmaxf(h00, 0.2f*h00) * at.x;                                       \
    h01 = fmaxf(h01, 0.2f*h01) * at.y;                                       \
    h02 = fmaxf(h02, 0.2f*h02) * at.z;                                       \
    h03 = fmaxf(h03, 0.2f*h03) * at.w;                                       \
    h10 = fmaxf(h10, 0.2f*h10) * at.x;                                       \
    h11 = fmaxf(h11, 0.2f*h11) * at.y;                                       \
    h12 = fmaxf(h12, 0.2f*h12) * at.z;                                       \
    h13 = fmaxf(h13, 0.2f*h13) * at.w;                                       \
    float g0 = (h00 + h01) + (h02 + h03);                                    \
    float g1 = (h10 + h11) + (h12 + h13);                                    \
    _Pragma("unroll")                                                        \
    for (int off = 1; off < 16; off <<= 1){                                  \
      g0 += __shfl_xor(g0, off);                                             \
      g1 += __shfl_xor(g1, off);                                             \
    }                                                                        \
    float p0 = (P0MASK) ? __expf(g0) : 0.f;                                  \
    float p1 = (V1OK) ? __expf(g1) : 0.f;                                    \
    s += p0 + p1;                                                            \
    a0 = fmaf(p0, x0, fmaf(p1, y0, a0));                                     \
    a1 = fmaf(p0, x1, fmaf(p1, y1, a1));                                     \
    a2 = fmaf(p0, x2, fmaf(p1, y2, a2));                                     \
    a3 = fmaf(p0, x3, fmaf(p1, y3, a3));                                     \
  }
#else
typedef float evt_t;
__device__ __forceinline__ float evload(const float* __restrict__ ea, int e, int l){
  return ea[(size_t)e*EAD + (l & 15)];
}
#define GAT_PAIR(X0, X1, EV0, EV1, V1OK, P0MASK)                             \
  {                                                                          \
    float x0 = b2f(X0.x), x1 = b2f(X0.y), x2 = b2f(X0.z), x3 = b2f(X0.w);    \
    float y0 = b2f(X1.x), y1 = b2f(X1.y), y2 = b2f(X1.z), y3 = b2f(X1.w);    \
    float h00 = x0 + r0, h01 = x1 + r1, h02 = x2 + r2, h03 = x3 + r3;        \
    float h10 = y0 + r0, h11 = y1 + r1, h12 = y2 + r2, h13 = y3 + r3;        \
    int ia0 = __float_as_int(EV0);                                           \
    int ia1 = __float_as_int(EV1);                                           \
    _Pragma("unroll")                                                        \
    for (int k = 0; k < EAD; ++k){                                           \
      float c0 = __int_as_float(__builtin_amdgcn_readlane(ia0, k));          \
      float c1 = __int_as_float(__builtin_amdgcn_readlane(ia1, k));          \
      float4 wv = *(const float4*)&sWeH[k*CW + 4*l];                         \
      h00 = fmaf(c0, wv.x, h00); h01 = fmaf(c0, wv.y, h01);                  \
      h02 = fmaf(c0, wv.z, h02); h03 = fmaf(c0, wv.w, h03);                  \
      h10 = fmaf(c1, wv.x, h10); h11 = fmaf(c1, wv.y, h11);                  \
      h12 = fmaf(c1, wv.z, h12); h13 = fmaf(c1, wv.w, h13);                  \
    }                                                                        \
    h00 = fmaxf(h00, 0.2f*h00) * at.x;                                       \
    h01 = fmaxf(h01, 0.2f*h01) * at.y;                                       \
    h02 = fmaxf(h02, 0.2f*h02) * at.z;                                       \
    h03 = fmaxf(h03, 0.2f*h03) * at.w;                                       \
    h10 = fmaxf(h10, 0.2f*h10) * at.x;                                       \
    h11 = fmaxf(h11, 0.2f*h11) * at.y;                                       \
    h12 = fmaxf(h12, 0.2f*h12) * at.z;                                       \
    h13 = fmaxf(h13, 0.2f*h13) * at.w;                                       \
    float g0 = (h00 + h01) + (h02 + h03);                                    \
    float g1 = (h10 + h11) + (h12 + h13);                                    \
    _Pragma("unroll")                                                        \
    for (int off = 1; off < 16; off <<= 1){                                  \
      g0 += __shfl_xor(g0, off);                                             \
      g1 += __shfl_xor(g1, off);                                             \
    }                                                                        \
    float p0 = (P0MASK) ? __expf(g0) : 0.f;                                  \
    float p1 = (V1OK) ? __expf(g1) : 0.f;                                    \
    s += p0 + p1;                                                            \
    a0 = fmaf(p0, x0, fmaf(p1, y0, a0));                                     \
    a1 = fmaf(p0, x1, fmaf(p1, y1, a1));                                     \
    a2 = fmaf(p0, x2, fmaf(p1, y2, a2));                                     \
    a3 = fmaf(p0, x3, fmaf(p1, y3, a3));                                     \
  }
#endif

// ---------------------------------------------------------------------------
// Merged fused GATv2, BOTH directions + ea colsum + h colsum epilogue.
// R5-proven structure: 2-pair rotation-free double buffer, high occupancy.
// ---------------------------------------------------------------------------
__global__ __launch_bounds__(256)
void gat2_kernel(const unsigned short* __restrict__ xlA_, const unsigned short* __restrict__ xrA_,
                 const float* __restrict__ WeA, const float* __restrict__ attA,
                 const float* __restrict__ biasA, const int2* __restrict__ csrA_,
                 const int* __restrict__ rsA_, float* __restrict__ houtA,
                 const unsigned short* __restrict__ xlB_, const unsigned short* __restrict__ xrB_,
                 const float* __restrict__ WeB, const float* __restrict__ attB,
                 const float* __restrict__ biasB, const int2* __restrict__ csrB_,
                 const int* __restrict__ rsB_, float* __restrict__ houtB,
                 const float* __restrict__ ea, float* __restrict__ mvec, int gsplit)
{
#if HAVE_DOT2
  __shared__ int sWeH[8*CW];     // [kpair][col] packed (We[2k][c], We[2k+1][c])
#else
  __shared__ float sWeH[16*CW];  // f32 We tile
#endif
  __shared__ float csum[4][16][4];
  int t = threadIdx.x, l = t & 63;
  int b = blockIdx.x;
  if (b < NEACOL){
    colsum_seg(b, NEACOL, (const float4*)ea, (long)NEDGE*EAD/4, 4,
               mvec + 128, 1.f/NEDGE, &csum[0][0][0]);
    return;
  }
  b -= NEACOL;
  int ngat = (int)gridDim.x - NEACOL;
  bool isA = b < gsplit;
  const unsigned short* xl = isA ? xlA_ : xlB_;
  const unsigned short* xr = isA ? xrA_ : xrB_;
  const float* We   = isA ? WeA   : WeB;
  const float* att  = isA ? attA  : attB;
  const float* bias = isA ? biasA : biasB;
  const int2* csr   = isA ? csrA_ : csrB_;
  const int* row_start = isA ? rsA_ : rsB_;
  float* hout = isA ? houtA : houtB;
  int ndst = isA ? NB : NP;
  int bid  = isA ? b : b - gsplit;
  int nblk = isA ? gsplit : ngat - gsplit;

#if HAVE_DOT2
  for (int i = t; i < 8*CW; i += 256){
    int j = i >> 8, c = i & 255;
    sWeH[i] = __builtin_bit_cast(int,
        __builtin_amdgcn_cvt_pkrtz(We[(2*j)*CW + c], We[(2*j+1)*CW + c]));
  }
#else
  for (int i = t*4; i < 16*CW; i += 1024)
    *(float4*)&sWeH[i] = *(const float4*)&We[i];
#endif
  __syncthreads();
#if HAVE_DOT2
  // hoist per-lane We columns to registers (loop-invariant, 32 VGPRs)
  int4 wreg[8];
  #pragma unroll
  for (int j = 0; j < 8; ++j) wreg[j] = *(const int4*)&sWeH[j*CW + 4*l];
#endif
  float4 at = *(const float4*)&att[4*l];
  float4 bi = *(const float4*)&bias[(l & 15)*4];
  float cs0 = 0.f, cs1 = 0.f, cs2 = 0.f, cs3 = 0.f;   // column-sum of outputs
  int wid = bid*4 + (t >> 6);
  int nw = nblk*4;
  for (int d = wid; d < ndst; d += nw){
    ushort4 ru = *(const ushort4*)(xr + (size_t)d*CW + 4*l);
    float r0 = b2f(ru.x), r1 = b2f(ru.y), r2 = b2f(ru.z), r3 = b2f(ru.w);
    int rs = row_start[d], re = row_start[d+1];
    float s = 0.f;
    float a0 = 0.f, a1 = 0.f, a2 = 0.f, a3 = 0.f;
    if (rs < re){
      int last = re - 1;
      #define CLMP(x) ((x) > last ? last : (x))
      int2 qA0 = csr[rs],         qA1 = csr[CLMP(rs+1)];
      int2 qB0 = csr[CLMP(rs+2)], qB1 = csr[CLMP(rs+3)];
      int2 nA0 = csr[CLMP(rs+4)], nA1 = csr[CLMP(rs+5)];
      int2 nB0 = csr[CLMP(rs+6)], nB1 = csr[CLMP(rs+7)];
      ushort4 xA0 = *(const ushort4*)(xl + (size_t)qA0.y*CW + 4*l);
      ushort4 xA1 = *(const ushort4*)(xl + (size_t)qA1.y*CW + 4*l);
      evt_t  evA0 = evload(ea, qA0.x, l);
      evt_t  evA1 = evload(ea, qA1.x, l);
      ushort4 xB0 = *(const ushort4*)(xl + (size_t)qB0.y*CW + 4*l);
      ushort4 xB1 = *(const ushort4*)(xl + (size_t)qB1.y*CW + 4*l);
      evt_t  evB0 = evload(ea, qB0.x, l);
      evt_t  evB1 = evload(ea, qB1.x, l);
      for (int i = rs; i < re; i += 4){
        int2 mA0 = csr[CLMP(i+8)],  mA1 = csr[CLMP(i+9)];
        int2 mB0 = csr[CLMP(i+10)], mB1 = csr[CLMP(i+11)];
        GAT_PAIR(xA0, xA1, evA0, evA1, (i+1 < re), true);
        xA0 = *(const ushort4*)(xl + (size_t)nA0.y*CW + 4*l);
        xA1 = *(const ushort4*)(xl + (size_t)nA1.y*CW + 4*l);
        evA0 = evload(ea, nA0.x, l);
        evA1 = evload(ea, nA1.x, l);
        nA0 = mA0; nA1 = mA1;
        GAT_PAIR(xB0, xB1, evB0, evB1, (i+3 < re), (i+2 < re));
        xB0 = *(const ushort4*)(xl + (size_t)nB0.y*CW + 4*l);
        xB1 = *(const ushort4*)(xl + (size_t)nB1.y*CW + 4*l);
        evB0 = evload(ea, nB0.x, l);
        evB1 = evload(ea, nB1.x, l);
        nB0 = mB0; nB1 = mB1;
      }
      #undef CLMP
    }
    float inv = 1.f / (s + 1e-16f);
    float v0 = a0*inv, v1 = a1*inv, v2 = a2*inv, v3 = a3*inv;
    v0 += __shfl_xor(v0, 16); v1 += __shfl_xor(v1, 16);
    v2 += __shfl_xor(v2, 16); v3 += __shfl_xor(v3, 16);
    v0 += __shfl_xor(v0, 32); v1 += __shfl_xor(v1, 32);
    v2 += __shfl_xor(v2, 32); v3 += __shfl_xor(v3, 32);
    if (l < 16){
      float4 o;
      o.x = geluf(v0*0.25f + bi.x);
      o.y = geluf(v1*0.25f + bi.y);
      o.z = geluf(v2*0.25f + bi.z);
      o.w = geluf(v3*0.25f + bi.w);
      *(float4*)(hout + (size_t)d*HID + 4*l) = o;
      cs0 += o.x; cs1 += o.y; cs2 += o.z; cs3 += o.w;
    }
  }
  // block-level column-sum reduce -> one atomic per column (64 per block)
  int w = t >> 6;
  if (l < 16){
    csum[w][l][0] = cs0; csum[w][l][1] = cs1;
    csum[w][l][2] = cs2; csum[w][l][3] = cs3;
  }
  __syncthreads();
  if (t < 64){
    int lq = t >> 2, j = t & 3;
    float sum = csum[0][lq][j] + csum[1][lq][j] + csum[2][lq][j] + csum[3][lq][j];
    float scale = isA ? (1.f/NB) : (1.f/NP);
    float* dst = isA ? (mvec + 64) : mvec;
    atomicAdd(&dst[t], sum * scale);
  }
}

// ---------------------------------------------------------------------------
// gemmcat: token-gather GEMM (tokb = concat(hp,hb,ea)[eids] @ Wet + bet).
// ---------------------------------------------------------------------------
__device__ void gemmcat_body(int bid, const float* __restrict__ hp, const float* __restrict__ hb,
                             const float* __restrict__ ea, const int* __restrict__ esrc,
                             const int* __restrict__ edst, const int* __restrict__ eids,
                             const float* __restrict__ W, const float* __restrict__ bias,
                             float* __restrict__ out)
{
  __shared__ float sAT[16][68];
  __shared__ float sB[16][68];
  __shared__ int sS[64], sD[64], sE[64];
  int t = threadIdx.x;
  int m0 = (bid >> 1)*64, n0 = (bid & 1)*64;
  if (t < 64){
    int e = eids[m0 + t];
    sS[t] = esrc[e]; sD[t] = edst[e]; sE[t] = e;
  }
  __syncthreads();
  int tr = t >> 4, tc = t & 15;
  float acc[4][4] = {};
  for (int k0 = 0; k0 < 144; k0 += 16){
    {
      int r = t >> 2, c = (t & 3) * 4;
      const float* src; int col = k0 + c;
      if (k0 < 64)       { src = hp + (size_t)sS[r]*HID; }
      else if (k0 < 128) { src = hb + (size_t)sD[r]*HID; col -= 64; }
      else               { src = ea + (size_t)sE[r]*EAD; col -= 128; }
      float4 va = *(const float4*)(src + col);
      sAT[c+0][r] = va.x; sAT[c+1][r] = va.y; sAT[c+2][r] = va.z; sAT[c+3][r] = va.w;
    }
    {
      int r = t >> 4, c = (t & 15) * 4;
      float4 vb = *(const float4*)(W + (size_t)(k0+r)*DD + n0 + c);
      *(float4*)&sB[r][c] = vb;
    }
    __syncthreads();
    #pragma unroll
    for (int k = 0; k < 16; ++k){
      float4 av = *(const float4*)&sAT[k][tr*4];
      float4 bv = *(const float4*)&sB[k][tc*4];
      acc[0][0] = fmaf(av.x, bv.x, acc[0][0]);
      acc[0][1] = fmaf(av.x, bv.y, acc[0][1]);
      acc[0][2] = fmaf(av.x, bv.z, acc[0][2]);
      acc[0][3] = fmaf(av.x, bv.w, acc[0][3]);
      acc[1][0] = fmaf(av.y, bv.x, acc[1][0]);
      acc[1][1] = fmaf(av.y, bv.y, acc[1][1]);
      acc[1][2] = fmaf(av.y, bv.z, acc[1][2]);
      acc[1][3] = fmaf(av.y, bv.w, acc[1][3]);
      acc[2][0] = fmaf(av.z, bv.x, acc[2][0]);
      acc[2][1] = fmaf(av.z, bv.y, acc[2][1]);
      acc[2][2] = fmaf(av.z, bv.z, acc[2][2]);
      acc[2][3] = fmaf(av.z, bv.w, acc[2][3]);
      acc[3][0] = fmaf(av.w, bv.x, acc[3][0]);
      acc[3][1] = fmaf(av.w, bv.y, acc[3][1]);
      acc[3][2] = fmaf(av.w, bv.z, acc[3][2]);
      acc[3][3] = fmaf(av.w, bv.w, acc[3][3]);
    }
    __syncthreads();
  }
  #pragma unroll
  for (int i = 0; i < 4; ++i){
    int gr = m0 + tr*4 + i;
    float4 v;
    v.x = acc[i][0] + bias[n0 + tc*4 + 0];
    v.y = acc[i][1] + bias[n0 + tc*4 + 1];
    v.z = acc[i][2] + bias[n0 + tc*4 + 2];
    v.w = acc[i][3] + bias[n0 + tc*4 + 3];
    *(float4*)(out + (size_t)gr*DD + n0 + tc*4) = v;
  }
}

// ---------------------------------------------------------------------------
// qstageF: one (column-quad q, k-chunk ch) unit of a 6-row GEMM stage.
// ---------------------------------------------------------------------------
template<int K, int N, int NC>
__device__ __forceinline__ void qstageF(const float* __restrict__ x,
                                        const float* __restrict__ W,
                                        float (&a)[6][4], int q, int ch)
{
  constexpr int NQ = N/4;
  constexpr int KC = K/NC;     // multiple of 4
  constexpr int J  = KC/4;     // power of 2
  const float4* wp = (const float4*)W + (size_t)(ch*KC)*NQ + q;
  const float* xb = x + ch*KC;
  float4 wv[KC];
  int kx[J];
  #pragma unroll
  for (int j = 0; j < J; ++j){
    int k4 = (j + ch) & (J-1);
    kx[j] = k4;
    wv[j*4+0] = wp[(size_t)(k4*4+0)*NQ];
    wv[j*4+1] = wp[(size_t)(k4*4+1)*NQ];
    wv[j*4+2] = wp[(size_t)(k4*4+2)*NQ];
    wv[j*4+3] = wp[(size_t)(k4*4+3)*NQ];
  }
  #pragma unroll
  for (int s = 0; s < 6; ++s){ a[s][0]=0.f; a[s][1]=0.f; a[s][2]=0.f; a[s][3]=0.f; }
  #pragma unroll
  for (int j = 0; j < J; ++j){
    #pragma unroll
    for (int s = 0; s < 6; ++s){
      float4 xv = *(const float4*)&xb[s*K + kx[j]*4];
      a[s][0]=fmaf(xv.x,wv[j*4+0].x,a[s][0]); a[s][0]=fmaf(xv.y,wv[j*4+1].x,a[s][0]);
      a[s][0]=fmaf(xv.z,wv[j*4+2].x,a[s][0]); a[s][0]=fmaf(xv.w,wv[j*4+3].x,a[s][0]);
      a[s][1]=fmaf(xv.x,wv[j*4+0].y,a[s][1]); a[s][1]=fmaf(xv.y,wv[j*4+1].y,a[s][1]);
      a[s][1]=fmaf(xv.z,wv[j*4+2].y,a[s][1]); a[s][1]=fmaf(xv.w,wv[j*4+3].y,a[s][1]);
      a[s][2]=fmaf(xv.x,wv[j*4+0].z,a[s][2]); a[s][2]=fmaf(xv.y,wv[j*4+1].z,a[s][2]);
      a[s][2]=fmaf(xv.z,wv[j*4+2].z,a[s][2]); a[s][2]=fmaf(xv.w,wv[j*4+3].z,a[s][2]);
      a[s][3]=fmaf(xv.x,wv[j*4+0].w,a[s][3]); a[s][3]=fmaf(xv.y,wv[j*4+1].w,a[s][3]);
      a[s][3]=fmaf(xv.z,wv[j*4+2].w,a[s][3]); a[s][3]=fmaf(xv.w,wv[j*4+3].w,a[s][3]);
    }
  }
  #pragma unroll
  for (int off = 1; off < NC; off <<= 1){
    #pragma unroll
    for (int s = 0; s < 6; ++s){
      a[s][0]+=__shfl_xor(a[s][0],off); a[s][1]+=__shfl_xor(a[s][1],off);
      a[s][2]+=__shfl_xor(a[s][2],off); a[s][3]+=__shfl_xor(a[s][3],off);
    }
  }
}

// ---------------------------------------------------------------------------
// xform body (256 threads): buildx + 2 encoder layers + ctxdot.
// Unit-loops stride 256; LN done in 2 passes of 4 waves.
// ---------------------------------------------------------------------------
__device__ void xform_body(const float* __restrict__ hist, const float* __restrict__ mvec,
                           const float* __restrict__ Wgs, const float* __restrict__ bgs,
                           const float* __restrict__ pos,
                           const float* __restrict__ Wqkv, const float* __restrict__ bqkv,
                           const float* __restrict__ Wo, const float* __restrict__ bo,
                           const float* __restrict__ ln1g, const float* __restrict__ ln1b,
                           const float* __restrict__ W1, const float* __restrict__ b1,
                           const float* __restrict__ W2, const float* __restrict__ b2,
                           const float* __restrict__ ln2g, const float* __restrict__ ln2b,
                           const float* __restrict__ Wc1, const float* __restrict__ bc1,
                           float* __restrict__ bias2)
{
  __shared__ float sx[SEQ*DD];       // current x
  __shared__ float sq[SEQ*3*DD];     // qkv
  __shared__ float sh[SEQ*512];      // ffn hidden
  __shared__ float st[SEQ*DD];       // attn-out / pre-LN2 buffer
  __shared__ float sc[4][6][6];
  __shared__ float smv[144];
  int t = threadIdx.x;

  // rows 0..4 = hist+pos ; mvec -> LDS
  for (int i = t; i < (SEQ-1)*DD; i += 256) sx[i] = hist[i] + pos[i];
  if (t < 144) smv[t] = mvec[t];
  __syncthreads();
  // row 5 = mvec @ Wgs + bgs + pos[5]   (32 quads x 8 chunks of 18 k)
  {
    int q = t >> 3, ch = t & 7;
    float4 wv[18];
    #pragma unroll
    for (int kk = 0; kk < 18; ++kk)
      wv[kk] = *(const float4*)&Wgs[(ch*18+kk)*DD + q*4];
    float a0=0.f,a1=0.f,a2=0.f,a3=0.f;
    #pragma unroll
    for (int kk = 0; kk < 18; ++kk){
      float xv = smv[ch*18+kk];
      a0=fmaf(xv,wv[kk].x,a0); a1=fmaf(xv,wv[kk].y,a1);
      a2=fmaf(xv,wv[kk].z,a2); a3=fmaf(xv,wv[kk].w,a3);
    }
    #pragma unroll
    for (int off = 1; off < 8; off <<= 1){
      a0+=__shfl_xor(a0,off); a1+=__shfl_xor(a1,off);
      a2+=__shfl_xor(a2,off); a3+=__shfl_xor(a3,off);
    }
    if (ch == 0){
      int n = q*4, base = (SEQ-1)*DD + n;
      sx[base+0]=a0+bgs[n+0]+pos[base+0];
      sx[base+1]=a1+bgs[n+1]+pos[base+1];
      sx[base+2]=a2+bgs[n+2]+pos[base+2];
      sx[base+3]=a3+bgs[n+3]+pos[base+3];
    }
  }
  __syncthreads();

  for (int lyr = 0; lyr < L; ++lyr){
    // qkv = x @ Wqkv + bqkv   (96 quads x NC=4 = 384 units)
    for (int u = t; u < 384; u += 256){
      int q = u >> 2, ch = u & 3;
      const float* wq = Wqkv + (size_t)lyr*DD*3*DD;
      const float* bq = bqkv + lyr*3*DD;
      float a[6][4];
      qstageF<128,384,4>(sx, wq, a, q, ch);
      if (ch == 0){
        int n = q*4;
        #pragma unroll
        for (int s = 0; s < 6; ++s){
          sq[s*384+n+0]=a[s][0]+bq[n+0];
          sq[s*384+n+1]=a[s][1]+bq[n+1];
          sq[s*384+n+2]=a[s][2]+bq[n+2];
          sq[s*384+n+3]=a[s][3]+bq[n+3];
        }
      }
    }
    __syncthreads();
    // scores
    if (t < 144){
      int h = t/36, r = t%36, qi = r/6, ki = r%6;
      float acc = 0.f;
      #pragma unroll
      for (int d2 = 0; d2 < 32; ++d2)
        acc = fmaf(sq[qi*384 + h*32 + d2], sq[ki*384 + 128 + h*32 + d2], acc);
      sc[h][qi][ki] = acc * 0.17677669529663687f;
    }
    __syncthreads();
    if (t < 24){
      int h = t/6, qi = t%6;
      float* row = sc[h][qi];
      float mx = row[0];
      #pragma unroll
      for (int k = 1; k < 6; ++k) mx = fmaxf(mx, row[k]);
      float sm = 0.f;
      #pragma unroll
      for (int k = 0; k < 6; ++k){ row[k] = __expf(row[k]-mx); sm += row[k]; }
      float inv = 1.f/sm;
      #pragma unroll
      for (int k = 0; k < 6; ++k) row[k] *= inv;
    }
    __syncthreads();
    // attention output -> st
    for (int i = t; i < SEQ*DD; i += 256){
      int s = i >> 7, n = i & 127, h = n >> 5, d2 = n & 31;
      float acc = 0.f;
      #pragma unroll
      for (int ki = 0; ki < 6; ++ki)
        acc = fmaf(sc[h][s][ki], sq[ki*384 + 256 + h*32 + d2], acc);
      st[i] = acc;
    }
    __syncthreads();
    // proj: st @ Wo + bo + resid(sx) -> sh   (32 quads x NC=16 = 512 units)
    for (int u = t; u < 512; u += 256){
      int q = u >> 4, ch = u & 15;
      float a[6][4];
      qstageF<128,128,16>(st, Wo + (size_t)lyr*DD*DD, a, q, ch);
      if (ch == 0){
        int n = q*4;
        const float* bop = bo + lyr*DD;
        #pragma unroll
        for (int s = 0; s < 6; ++s){
          sh[s*128+n+0]=a[s][0]+bop[n+0]+sx[s*128+n+0];
          sh[s*128+n+1]=a[s][1]+bop[n+1]+sx[s*128+n+1];
          sh[s*128+n+2]=a[s][2]+bop[n+2]+sx[s*128+n+2];
          sh[s*128+n+3]=a[s][3]+bop[n+3]+sx[s*128+n+3];
        }
      }
    }
    __syncthreads();
    // LN1: sh -> sx (2 passes of 4 waves)
    {
      int lw = t & 63;
      const float* g = ln1g + lyr*DD; const float* be = ln1b + lyr*DD;
      for (int row = (t >> 6); row < SEQ; row += 4){
        float v0 = sh[row*DD + lw], v1 = sh[row*DD + 64 + lw];
        float sm = v0 + v1;
        #pragma unroll
        for (int off = 1; off < 64; off <<= 1) sm += __shfl_xor(sm, off);
        float mean = sm * 0.0078125f;
        float d0 = v0-mean, d1 = v1-mean;
        float qv = d0*d0 + d1*d1;
        #pragma unroll
        for (int off = 1; off < 64; off <<= 1) qv += __shfl_xor(qv, off);
        float inv = rsqrtf(qv*0.0078125f + 1e-5f);
        sx[row*DD + lw]      = d0*inv*g[lw] + be[lw];
        sx[row*DD + 64 + lw] = d1*inv*g[64+lw] + be[64+lw];
      }
    }
    __syncthreads();
    // ffn1: sx @ W1 -> gelu -> sh[6][512]   (128 quads x NC=4 = 512 units)
    for (int u = t; u < 512; u += 256){
      int q = u >> 2, ch = u & 3;
      const float* w1 = W1 + (size_t)lyr*DD*512;
      const float* b1p = b1 + lyr*512;
      float a[6][4];
      qstageF<128,512,4>(sx, w1, a, q, ch);
      if (ch == 0){
        int n = q*4;
        #pragma unroll
        for (int s = 0; s < 6; ++s){
          sh[s*512+n+0]=geluf(a[s][0]+b1p[n+0]);
          sh[s*512+n+1]=geluf(a[s][1]+b1p[n+1]);
          sh[s*512+n+2]=geluf(a[s][2]+b1p[n+2]);
          sh[s*512+n+3]=geluf(a[s][3]+b1p[n+3]);
        }
      }
    }
    __syncthreads();
    // ffn2: sh @ W2 + b2 + resid(sx) -> st   (32 quads x NC=16 = 512 units)
    for (int u = t; u < 512; u += 256){
      int q = u >> 4, ch = u & 15;
      const float* w2 = W2 + (size_t)lyr*512*DD;
      const float* b2p = b2 + lyr*DD;
      float a[6][4];
      qstageF<512,128,16>(sh, w2, a, q, ch);
      if (ch == 0){
        int n = q*4;
        #pragma unroll
        for (int s = 0; s < 6; ++s){
          st[s*128+n+0]=a[s][0]+b2p[n+0]+sx[s*128+n+0];
          st[s*128+n+1]=a[s][1]+b2p[n+1]+sx[s*128+n+1];
          st[s*128+n+2]=a[s][2]+b2p[n+2]+sx[s*128+n+2];
          st[s*128+n+3]=a[s][3]+b2p[n+3]+sx[s*128+n+3];
        }
      }
    }
    __syncthreads();
    // LN2: st -> sx (2 passes of 4 waves)
    {
      int lw = t & 63;
      const float* g = ln2g + lyr*DD; const float* be = ln2b + lyr*DD;
      for (int row = (t >> 6); row < SEQ; row += 4){
        float v0 = st[row*DD + lw], v1 = st[row*DD + 64 + lw];
        float sm = v0 + v1;
        #pragma unroll
        for (int off = 1; off < 64; off <<= 1) sm += __shfl_xor(sm, off);
        float mean = sm * 0.0078125f;
        float d0 = v0-mean, d1 = v1-mean;
        float qv = d0*d0 + d1*d1;
        #pragma unroll
        for (int off = 1; off < 64; off <<= 1) qv += __shfl_xor(qv, off);
        float inv = rsqrtf(qv*0.0078125f + 1e-5f);
        sx[row*DD + lw]      = d0*inv*g[lw] + be[lw];
        sx[row*DD + 64 + lw] = d1*inv*g[64+lw] + be[64+lw];
      }
    }
    __syncthreads();
  }
  // ctxdot: bias2[n] = bc1[n] + sum_k ctx[k]*Wc1[128+k][n]  (32 quads x 8 chunks)
  {
    int q = t >> 3, ch = t & 7;
    const float4* wp = (const float4*)(Wc1 + (size_t)DD*DD) + (size_t)(ch*16)*32 + q;
    const float* xb = &sx[(SEQ-1)*DD + ch*16];
    float4 wv[16];
    int kx[4];
    #pragma unroll
    for (int j = 0; j < 4; ++j){
      int k4 = (j + ch) & 3;
      kx[j] = k4;
      wv[j*4+0] = wp[(size_t)(k4*4+0)*32];
      wv[j*4+1] = wp[(size_t)(k4*4+1)*32];
      wv[j*4+2] = wp[(size_t)(k4*4+2)*32];
      wv[j*4+3] = wp[(size_t)(k4*4+3)*32];
    }
    float a0=0.f,a1=0.f,a2=0.f,a3=0.f;
    #pragma unroll
    for (int j = 0; j < 4; ++j){
      float4 xv = *(const float4*)&xb[kx[j]*4];
      a0=fmaf(xv.x,wv[j*4+0].x,a0); a0=fmaf(xv.y,wv[j*4+1].x,a0);
      a0=fmaf(xv.z,wv[j*4+2].x,a0); a0=fmaf(xv.w,wv[j*4+3].x,a0);
      a1=fmaf(xv.x,wv[j*4+0].y,a1); a1=fmaf(xv.y,wv[j*4+1].y,a1);
      a1=fmaf(xv.z,wv[j*4+2].y,a1); a1=fmaf(xv.w,wv[j*4+3].y,a1);
      a2=fmaf(xv.x,wv[j*4+0].z,a2); a2=fmaf(xv.y,wv[j*4+1].z,a2);
      a2=fmaf(xv.z,wv[j*4+2].z,a2); a2=fmaf(xv.w,wv[j*4+3].z,a2);
      a3=fmaf(xv.x,wv[j*4+0].w,a3); a3=fmaf(xv.y,wv[j*4+1].w,a3);
      a3=fmaf(xv.z,wv[j*4+2].w,a3); a3=fmaf(xv.w,wv[j*4+3].w,a3);
    }
    #pragma unroll
    for (int off = 1; off < 8; off <<= 1){
      a0+=__shfl_xor(a0,off); a1+=__shfl_xor(a1,off);
      a2+=__shfl_xor(a2,off); a3+=__shfl_xor(a3,off);
    }
    if (ch == 0){
      int n = q*4;
      bias2[n+0]=a0+bc1[n+0];
      bias2[n+1]=a1+bc1[n+1];
      bias2[n+2]=a2+bc1[n+2];
      bias2[n+3]=a3+bc1[n+3];
    }
  }
}

// ---------------------------------------------------------------------------
// k3: gemmcat (blocks 0..255) || xform (block 256) merged.
// ---------------------------------------------------------------------------
__global__ __launch_bounds__(256)
void k3_gemmcat_xform(const float* __restrict__ hp, const float* __restrict__ hb,
                      const float* __restrict__ ea, const int* __restrict__ esrc,
                      const int* __restrict__ edst, const int* __restrict__ eids,
                      const float* __restrict__ Wet, const float* __restrict__ bet,
                      float* __restrict__ tokb,
                      const float* __restrict__ hist, const float* __restrict__ mvec,
                      const float* __restrict__ Wgs, const float* __restrict__ bgs,
                      const float* __restrict__ pos,
                      const float* __restrict__ Wqkv, const float* __restrict__ bqkv,
                      const float* __restrict__ Wo, const float* __restrict__ bo,
                      const float* __restrict__ ln1g, const float* __restrict__ ln1b,
                      const float* __restrict__ W1, const float* __restrict__ b1,
                      const float* __restrict__ W2, const float* __restrict__ b2,
                      const float* __restrict__ ln2g, const float* __restrict__ ln2b,
                      const float* __restrict__ Wc1, const float* __restrict__ bc1,
                      float* __restrict__ bias2)
{
  if (blockIdx.x < 256){
    gemmcat_body(blockIdx.x, hp, hb, ea, esrc, edst, eids, Wet, bet, tokb);
  } else {
    xform_body(hist, mvec, Wgs, bgs, pos, Wqkv, bqkv, Wo, bo, ln1g, ln1b,
               W1, b1, W2, b2, ln2g, ln2b, Wc1, bc1, bias2);
  }
}

// ---------------------------------------------------------------------------
// cls: fused hid = gelu(tokb @ Wc1[0:128] + bias2) ; out = hid @ Wc2 + bc2.
// ---------------------------------------------------------------------------
__global__ __launch_bounds__(256)
void cls_kernel(const float* __restrict__ A, const float* __restrict__ W,
                const float* __restrict__ bias2, const float* __restrict__ Wc2,
                const float* __restrict__ bc2, float* __restrict__ out)
{
  __shared__ float sAT[16][68];
  __shared__ float sB[16][132];
  __shared__ float sH[64][129];
  int t = threadIdx.x;
  int m0 = blockIdx.x * 64;
  int tr = t >> 4, tc = t & 15;
  float acc[4][8] = {};
  for (int k0 = 0; k0 < DD; k0 += 16){
    {
      int r = t >> 2, c = (t & 3) * 4;
      float4 va = *(const float4*)(A + (size_t)(m0+r)*DD + k0 + c);
      sAT[c+0][r] = va.x; sAT[c+1][r] = va.y; sAT[c+2][r] = va.z; sAT[c+3][r] = va.w;
    }
    {
      int r = t >> 4, c = (t & 15) * 8;
      float4 b0 = *(const float4*)(W + (size_t)(k0+r)*DD + c);
      float4 b1 = *(const float4*)(W + (size_t)(k0+r)*DD + c + 4);
      *(float4*)&sB[r][c] = b0;
      *(float4*)&sB[r][c+4] = b1;
    }
    __syncthreads();
    #pragma unroll
    for (int k = 0; k < 16; ++k){
      float4 av = *(const float4*)&sAT[k][tr*4];
      float4 b0 = *(const float4*)&sB[k][tc*8];
      float4 b1 = *(const float4*)&sB[k][tc*8+4];
      #pragma unroll
      for (int i = 0; i < 4; ++i){
        float avi = (i==0)?av.x:(i==1)?av.y:(i==2)?av.z:av.w;
        acc[i][0] = fmaf(avi, b0.x, acc[i][0]);
        acc[i][1] = fmaf(avi, b0.y, acc[i][1]);
        acc[i][2] = fmaf(avi, b0.z, acc[i][2]);
        acc[i][3] = fmaf(avi, b0.w, acc[i][3]);
        acc[i][4] = fmaf(avi, b1.x, acc[i][4]);
        acc[i][5] = fmaf(avi, b1.y, acc[i][5]);
        acc[i][6] = fmaf(avi, b1.z, acc[i][6]);
        acc[i][7] = fmaf(avi, b1.w, acc[i][7]);
      }
    }
    __syncthreads();
  }
  // epilogue: gelu(acc + bias2) -> sH
  #pragma unroll
  for (int i = 0; i < 4; ++i){
    #pragma unroll
    for (int j = 0; j < 8; ++j){
      sH[tr*4+i][tc*8+j] = geluf(acc[i][j] + bias2[tc*8+j]);
    }
  }
  __syncthreads();
  // head: out[m0+row][c] = sH[row] . Wc2[:,c] + bc2[c]
  if (t < 64){
    float a10[NCLS];
    #pragma unroll
    for (int c = 0; c < NCLS; ++c) a10[c] = bc2[c];
    for (int k = 0; k < DD; ++k){
      float hv = sH[t][k];
      #pragma unroll
      for (int c = 0; c < NCLS; ++c)
        a10[c] = fmaf(hv, Wc2[k*NCLS + c], a10[c]);
    }
    #pragma unroll
    for (int c = 0; c < NCLS; ++c)
      out[(size_t)(m0+t)*NCLS + c] = a10[c];
  }
}

extern "C" void kernel_launch(void* const* d_in, const int* in_sizes, int n_in,
                              void* d_out, int out_size, void* d_ws, size_t ws_size,
                              hipStream_t stream){
  (void)in_sizes; (void)n_in; (void)out_size; (void)ws_size;
  const float* pitcher = (const float*)d_in[0];
  const float* batter  = (const float*)d_in[1];
  const float* eattr   = (const float*)d_in[2];
  const float* hist    = (const float*)d_in[3];
  const float* Wp = (const float*)d_in[4];
  const float* bp = (const float*)d_in[5];
  const float* Wb = (const float*)d_in[6];
  const float* bb = (const float*)d_in[7];
  const float* rel_Wl  = (const float*)d_in[8];
  const float* rel_bl  = (const float*)d_in[9];
  const float* rel_Wr  = (const float*)d_in[10];
  const float* rel_br  = (const float*)d_in[11];
  const float* rel_We  = (const float*)d_in[12];
  const float* rel_att = (const float*)d_in[13];
  const float* rel_bias= (const float*)d_in[14];
  const float* rev_Wl  = (const float*)d_in[15];
  const float* rev_bl  = (const float*)d_in[16];
  const float* rev_Wr  = (const float*)d_in[17];
  const float* rev_br  = (const float*)d_in[18];
  const float* rev_We  = (const float*)d_in[19];
  const float* rev_att = (const float*)d_in[20];
  const float* rev_bias= (const float*)d_in[21];
  const float* Wgs = (const float*)d_in[22];
  const float* bgs = (const float*)d_in[23];
  const float* Wet = (const float*)d_in[24];
  const float* bet = (const float*)d_in[25];
  const float* pos = (const float*)d_in[26];
  const float* Wqkv= (const float*)d_in[27];
  const float* bqkv= (const float*)d_in[28];
  const float* Wo  = (const float*)d_in[29];
  const float* bo  = (const float*)d_in[30];
  const float* ln1g= (const float*)d_in[31];
  const float* ln1b= (const float*)d_in[32];
  const float* W1  = (const float*)d_in[33];
  const float* b1  = (const float*)d_in[34];
  const float* W2  = (const float*)d_in[35];
  const float* b2  = (const float*)d_in[36];
  const float* ln2g= (const float*)d_in[37];
  const float* ln2b= (const float*)d_in[38];
  const float* Wc1 = (const float*)d_in[39];
  const float* bc1 = (const float*)d_in[40];
  const float* Wc2 = (const float*)d_in[41];
  const float* bc2 = (const float*)d_in[42];
  const int* esrc = (const int*)d_in[43];
  const int* edst = (const int*)d_in[44];
  const int* eids = (const int*)d_in[45];

  // workspace carve-out
  char* w = (char*)d_ws;
  size_t off = 0;
  auto alloc = [&](size_t bytes)->void*{
    void* p = (void*)(w + off);
    off += (bytes + 255) & ~(size_t)255;
    return p;
  };
  unsigned short* px_bf  = (unsigned short*)alloc((size_t)NP*HID*2);
  unsigned short* bx_bf  = (unsigned short*)alloc((size_t)NB*HID*2);
  float*          hp     = (float*)alloc((size_t)NP*HID*4);
  float*          hb     = (float*)alloc((size_t)NB*HID*4);
  unsigned short* xlA    = (unsigned short*)alloc((size_t)NP*CW*2);  // rel: src=pitcher
  unsigned short* xrA    = (unsigned short*)alloc((size_t)NB*CW*2);  // rel: dst=batter
  unsigned short* xlB    = (unsigned short*)alloc((size_t)NB*CW*2);  // rev: src=batter
  unsigned short* xrB    = (unsigned short*)alloc((size_t)NP*CW*2);  // rev: dst=pitcher
  int*            degAB  = (int*)alloc((size_t)(NB+NP)*4);
  int*            degA   = degAB;
  int*            degB   = degAB + NB;
  int*            rowstA = (int*)alloc((size_t)(NB+1)*4);
  int*            rowstB = (int*)alloc((size_t)(NP+1)*4);
  int*            cursA  = (int*)alloc((size_t)NB*4);
  int*            cursB  = (int*)alloc((size_t)NP*4);
  int2*           csrA   = (int2*)alloc((size_t)NEDGE*8);
  int2*           csrB   = (int2*)alloc((size_t)NEDGE*8);
  float*          mvec   = (float*)alloc(144*4);
  float*          bias2  = (float*)alloc(DD*4);
  // alias over dead GAT buffer (xlA dead after gat2):
  float*          tokb   = (float*)xlA;   // BEDGE*DD*4 = 4.19MB <= 5.12MB

  const int nbCount = (NEDGE + 255)/256;          // 1172
  const int nbP = (NP + 63)/64;                   // 157
  const int nbB = (NB + 63)/64;                   // 469

  // k1: degree count (both dirs) || node encoders
  hipMemsetAsync(degAB, 0, (size_t)(NB+NP)*4, stream);
  k1_count_enc<<<nbCount + nbP + nbB, 256, 0, stream>>>(
      edst, esrc, degA, degB,
      pitcher, Wp, bp, px_bf, batter, Wb, bb, bx_bf, nbCount, nbP);

  // scan both CSRs (2 blocks) + zero mvec
  scan2_kernel<<<2, 1024, 0, stream>>>(degA, rowstA, cursA, NB,
                                       degB, rowstB, cursB, NP, mvec);

  // k2: CSR scatter || all four projection GEMMs
  k2_scatter_proj<<<nbCount + 2*nbP + 2*nbB, 256, 0, stream>>>(
      edst, esrc, cursA, cursB, csrA, csrB, px_bf, bx_bf,
      rel_Wl, rel_bl, rel_Wr, rel_br, rev_Wl, rev_bl, rev_Wr, rev_br,
      xlA, xrA, xlB, xrB, nbCount, nbP, nbB);

  // merged GAT (both dirs) + ea colsum + h colsum epilogue
  gat2_kernel<<<NEACOL + 4096, 256, 0, stream>>>(
      xlA, xrA, rel_We, rel_att, rel_bias, csrA, rowstA, hb,
      xlB, xrB, rev_We, rev_att, rev_bias, csrB, rowstB, hp,
      eattr, mvec, 2048);

  // k3: token-gather GEMM (blocks 0..255) || fused transformer (block 256)
  k3_gemmcat_xform<<<257, 256, 0, stream>>>(
      hp, hb, eattr, esrc, edst, eids, Wet, bet, tokb,
      hist, mvec, Wgs, bgs, pos, Wqkv, bqkv, Wo, bo, ln1g, ln1b,
      W1, b1, W2, b2, ln2g, ln2b, Wc1, bc1, bias2);

  // classifier (hid GEMM + head fused)
  cls_kernel<<<BEDGE/64, 256, 0, stream>>>(tokb, Wc1, bias2, Wc2, bc2, (float*)d_out);
}

// Round 11
// 375.094 us; speedup vs baseline: 1.1096x; 1.1096x over previous
//
#include <hip/hip_runtime.h>
#include <math.h>

// Problem constants (match reference)
#define NP 10000
#define NB 30000
#define NEDGE 300000
#define BEDGE 8192
#define EAD 16
#define HID 64
#define GH 4
#define CW 256      // GH*HID
#define DD 128
#define SEQ 6
#define NCLS 10
#define L 2
#define NEACOL 64   // ea-colsum blocks folded into gat2 grid

#if defined(__has_builtin)
#  if __has_builtin(__builtin_amdgcn_fdot2)
#    define HAVE_DOT2 1
#  else
#    define HAVE_DOT2 0
#  endif
#else
#  define HAVE_DOT2 0
#endif

typedef _Float16 h16x2 __attribute__((ext_vector_type(2)));

__device__ __forceinline__ float geluf(float x){
  // jax.nn.gelu(approximate=False)
  return 0.5f * x * (1.0f + erff(x * 0.7071067811865475f));
}

__device__ __forceinline__ float b2f(unsigned short u){
  unsigned v = ((unsigned)u) << 16;
  return __int_as_float(v);
}
__device__ __forceinline__ unsigned short f2b(float f){
  unsigned x = __float_as_uint(f);
  unsigned r = x + 0x7FFF + ((x >> 16) & 1);   // round-to-nearest-even
  return (unsigned short)(r >> 16);
}

typedef __attribute__((ext_vector_type(8))) short bf16x8;
typedef __attribute__((ext_vector_type(4))) float f32x4;

// ---------------------------------------------------------------------------
// MFMA GEMM body: out_bf16[M][N] = (GELU?)(A[M][KQ] @ W[KQ][N] + bias[N])
// Epilogue routes the C tile through LDS (reusing sWt after a barrier) so
// global stores are coalesced int4 (16B/lane) instead of scalar ushort.
// ---------------------------------------------------------------------------
template<int KQ, int NTILES, bool A_F32, bool GELU>
__device__ __forceinline__
void mfma_gemm_body(int bid, const void* __restrict__ Av, const float* __restrict__ W,
                    const float* __restrict__ bias, unsigned short* __restrict__ out,
                    int M, unsigned short* __restrict__ sWt)
{
  constexpr int N  = NTILES * 16;
  constexpr int KP = KQ + 8;
  constexpr int NP8 = N + 8;     // padded LDS row stride (ushorts), 16B-aligned
  int t = threadIdx.x, w = t >> 6, l = t & 63;
  int c = l & 15, g = l >> 4;
  for (int idx = t; idx < KQ*N; idx += 256){
    int k = idx / N, n = idx - k*N;
    sWt[n*KP + k] = f2b(W[idx]);
  }
  __syncthreads();
  int rowbase = bid*64 + w*16;
  int arow = rowbase + c; if (arow > M-1) arow = M-1;   // clamp (no OOB reads)
  f32x4 acc[NTILES] = {};
  #pragma unroll
  for (int ks = 0; ks < KQ/32; ++ks){
    int koff = ks*32 + g*8;
    bf16x8 a;
    if constexpr (A_F32){
      const float* Af = (const float*)Av + (size_t)arow*KQ + koff;
      float4 f0 = *(const float4*)Af;
      float4 f1 = *(const float4*)(Af + 4);
      a[0]=(short)f2b(f0.x); a[1]=(short)f2b(f0.y); a[2]=(short)f2b(f0.z); a[3]=(short)f2b(f0.w);
      a[4]=(short)f2b(f1.x); a[5]=(short)f2b(f1.y); a[6]=(short)f2b(f1.z); a[7]=(short)f2b(f1.w);
    } else {
      a = *(const bf16x8*)((const unsigned short*)Av + (size_t)arow*KQ + koff);
    }
    #pragma unroll
    for (int nt = 0; nt < NTILES; ++nt){
      bf16x8 b = *(const bf16x8*)&sWt[(nt*16 + c)*KP + koff];
      acc[nt] = __builtin_amdgcn_mfma_f32_16x16x32_bf16(a, b, acc[nt], 0, 0, 0);
    }
  }
  // epilogue: acc -> LDS (bias/gelu/bf16), then coalesced 16B global stores
  __syncthreads();     // all waves done reading sWt
  #pragma unroll
  for (int nt = 0; nt < NTILES; ++nt){
    #pragma unroll
    for (int j = 0; j < 4; ++j){
      float v = acc[nt][j] + bias[nt*16 + c];
      if (GELU) v = geluf(v);
      sWt[(w*16 + g*4 + j)*NP8 + nt*16 + c] = f2b(v);
    }
  }
  __syncthreads();
  int blockrow0 = bid*64;
  constexpr int C8 = N/8;        // 16B chunks per row
  for (int idx = t; idx < 64*C8; idx += 256){
    int row = idx / C8, c8 = idx - row*C8;
    if (blockrow0 + row < M){
      *(int4*)(out + (size_t)(blockrow0 + row)*N + c8*8) =
          *(const int4*)&sWt[row*NP8 + c8*8];
    }
  }
}

// ---------------------------------------------------------------------------
// k1: edge-degree count (both dirs) || node encoders (pitcher+batter) merged.
// ---------------------------------------------------------------------------
__global__ __launch_bounds__(256)
void k1_count_enc(const int* __restrict__ edst, const int* __restrict__ esrc,
                  int* __restrict__ degA, int* __restrict__ degB,
                  const float* __restrict__ pit, const float* __restrict__ Wp,
                  const float* __restrict__ bp, unsigned short* __restrict__ px,
                  const float* __restrict__ bat, const float* __restrict__ Wb,
                  const float* __restrict__ bb, unsigned short* __restrict__ bx,
                  int nbCount, int nbP)
{
  __shared__ unsigned short sWt[64*136];   // N=64, KP=136 (>= 64*72 for epilogue)
  int b = blockIdx.x;
  if (b < nbCount){
    int i = b*256 + threadIdx.x;
    if (i < NEDGE){
      atomicAdd(&degA[edst[i]], 1);
      atomicAdd(&degB[esrc[i]], 1);
    }
  } else if (b < nbCount + nbP){
    mfma_gemm_body<128,4,true,true>(b - nbCount, pit, Wp, bp, px, NP, sWt);
  } else {
    mfma_gemm_body<128,4,true,true>(b - nbCount - nbP, bat, Wb, bb, bx, NB, sWt);
  }
}

// ---------------------------------------------------------------------------
// scan: shuffle-based exclusive scan, 4 elems/thread
// ---------------------------------------------------------------------------
__device__ void scan_dev(const int* __restrict__ deg, int* __restrict__ row_start,
                         int* __restrict__ cursor, int n){
  __shared__ int wsum[16];
  __shared__ int sbase;
  int t = threadIdx.x, w = t >> 6, l = t & 63;
  if (t == 0) sbase = 0;
  __syncthreads();
  for (int base = 0; base < n; base += 4096){
    int i = base + t*4;
    int4 v = make_int4(0,0,0,0);
    if (i < n) v = *(const int4*)(deg + i);
    int tsum = v.x + v.y + v.z + v.w;
    int x = tsum;
    #pragma unroll
    for (int off = 1; off < 64; off <<= 1){
      int y = __shfl_up(x, off);
      if (l >= off) x += y;
    }
    if (l == 63) wsum[w] = x;
    __syncthreads();
    int woff = 0, tot = 0;
    #pragma unroll
    for (int ww = 0; ww < 16; ++ww){
      int wv = wsum[ww];
      if (ww < w) woff += wv;
      tot += wv;
    }
    int excl = sbase + woff + x - tsum;
    if (i < n){
      int e1 = excl + v.x, e2 = excl + v.x + v.y, e3 = excl + v.x + v.y + v.z;
      row_start[i]   = excl; cursor[i]   = excl;
      row_start[i+1] = e1;   cursor[i+1] = e1;
      row_start[i+2] = e2;   cursor[i+2] = e2;
      row_start[i+3] = e3;   cursor[i+3] = e3;
    }
    __syncthreads();
    if (t == 0) sbase += tot;
    __syncthreads();
  }
  if (t == 0) row_start[n] = sbase;
}

__global__ __launch_bounds__(1024)
void scan2_kernel(const int* __restrict__ degA, int* __restrict__ rsA, int* __restrict__ curA, int nA,
                  const int* __restrict__ degB, int* __restrict__ rsB, int* __restrict__ curB, int nB,
                  float* __restrict__ mvec){
  if (blockIdx.x == 0){
    scan_dev(degA, rsA, curA, nA);
  } else {
    if (threadIdx.x < 144) mvec[threadIdx.x] = 0.f;   // zero mvec for colsum atomics
    scan_dev(degB, rsB, curB, nB);
  }
}

// ---------------------------------------------------------------------------
// k2: CSR scatter (both dirs) || all 4 GAT projection GEMMs merged.
// ---------------------------------------------------------------------------
__global__ __launch_bounds__(256)
void k2_scatter_proj(const int* __restrict__ edst, const int* __restrict__ esrc,
                     int* __restrict__ curA, int* __restrict__ curB,
                     int2* __restrict__ csrA, int2* __restrict__ csrB,
                     const unsigned short* __restrict__ px, const unsigned short* __restrict__ bx,
                     const float* __restrict__ rel_Wl, const float* __restrict__ rel_bl,
                     const float* __restrict__ rel_Wr, const float* __restrict__ rel_br,
                     const float* __restrict__ rev_Wl, const float* __restrict__ rev_bl,
                     const float* __restrict__ rev_Wr, const float* __restrict__ rev_br,
                     unsigned short* __restrict__ xlA, unsigned short* __restrict__ xrA,
                     unsigned short* __restrict__ xlB, unsigned short* __restrict__ xrB,
                     int nbScat, int nbP, int nbB)
{
  __shared__ unsigned short sWt[256*72];   // N=256, KP=72 (>= 64*264 for epilogue)
  int b = blockIdx.x;
  if (b < nbScat){
    int i = b*256 + threadIdx.x;
    if (i < NEDGE){
      int d = edst[i], s = esrc[i];
      int p = atomicAdd(&curA[d], 1);
      csrA[p] = make_int2(i, s);
      int q = atomicAdd(&curB[s], 1);
      csrB[q] = make_int2(i, d);
    }
  } else {
    b -= nbScat;
    if (b < nbP)               mfma_gemm_body<64,16,false,false>(b,            px, rel_Wl, rel_bl, xlA, NP, sWt);
    else if (b < nbP + nbB)    mfma_gemm_body<64,16,false,false>(b-nbP,        bx, rel_Wr, rel_br, xrA, NB, sWt);
    else if (b < nbP + 2*nbB)  mfma_gemm_body<64,16,false,false>(b-nbP-nbB,    bx, rev_Wl, rev_bl, xlB, NB, sWt);
    else                       mfma_gemm_body<64,16,false,false>(b-nbP-2*nbB,  px, rev_Wr, rev_br, xrB, NP, sWt);
  }
}

// ---------------------------------------------------------------------------
// Vectorized column-mean segment (used for ea inside gat2 grid).
// ---------------------------------------------------------------------------
__device__ __forceinline__ void colsum_seg(int bid, int nb, const float4* __restrict__ in4,
                                           long total4, int n4, float* __restrict__ out,
                                           float scale, float* lds){
  int t = threadIdx.x, l = t & 63, w = t >> 6;
  long gid = (long)bid*256 + t;
  long stride = (long)nb*256;
  float4 acc = make_float4(0.f,0.f,0.f,0.f);
  for (long i = gid; i < total4; i += stride){
    float4 v = in4[i];
    acc.x += v.x; acc.y += v.y; acc.z += v.z; acc.w += v.w;
  }
  for (int off = n4; off < 64; off <<= 1){
    acc.x += __shfl_xor(acc.x, off);
    acc.y += __shfl_xor(acc.y, off);
    acc.z += __shfl_xor(acc.z, off);
    acc.w += __shfl_xor(acc.w, off);
  }
  if (l < n4) *(float4*)&lds[(w*n4 + l)*4] = acc;
  __syncthreads();
  if (t < n4*4){
    float sum = lds[t] + lds[n4*4 + t] + lds[2*n4*4 + t] + lds[3*n4*4 + t];
    atomicAdd(&out[t], sum * scale);
  }
  __syncthreads();
}

// ---------------------------------------------------------------------------
// GAT pair-compute (R5-verified math, no online-max). DOT2 / f32 fallback.
// DOT2 path reads the per-lane We columns from REGISTERS (wreg[8], hoisted
// once after staging): loop-invariant, 32 VGPRs. If the allocator refuses,
// worst case it re-reads LDS (status quo).
// ---------------------------------------------------------------------------
#if HAVE_DOT2
typedef int evt_t;
__device__ __forceinline__ int evload(const float* __restrict__ ea, int e, int l){
  float2 fv = *(const float2*)(ea + (size_t)e*EAD + 2*(l & 7));
  return __builtin_bit_cast(int, __builtin_amdgcn_cvt_pkrtz(fv.x, fv.y));
}
#define GAT_PAIR(X0, X1, EV0, EV1, V1OK, P0MASK)                             \
  {                                                                          \
    float x0 = b2f(X0.x), x1 = b2f(X0.y), x2 = b2f(X0.z), x3 = b2f(X0.w);    \
    float y0 = b2f(X1.x), y1 = b2f(X1.y), y2 = b2f(X1.z), y3 = b2f(X1.w);    \
    float h00 = x0 + r0, h01 = x1 + r1, h02 = x2 + r2, h03 = x3 + r3;        \
    float h10 = y0 + r0, h11 = y1 + r1, h12 = y2 + r2, h13 = y3 + r3;        \
    _Pragma("unroll")                                                        \
    for (int j = 0; j < 8; ++j){                                             \
      int c0 = __builtin_amdgcn_readlane(EV0, j);                            \
      int c1 = __builtin_amdgcn_readlane(EV1, j);                            \
      h16x2 e0 = __builtin_bit_cast(h16x2, c0);                              \
      h16x2 e1 = __builtin_bit_cast(h16x2, c1);                              \
      int4 wr = wreg[j];                                                     \
      h16x2 w0 = __builtin_bit_cast(h16x2, wr.x);                            \
      h16x2 w1 = __builtin_bit_cast(h16x2, wr.y);                            \
      h16x2 w2 = __builtin_bit_cast(h16x2, wr.z);                            \
      h16x2 w3 = __builtin_bit_cast(h16x2, wr.w);                            \
      h00 = __builtin_amdgcn_fdot2(e0, w0, h00, false);                      \
      h01 = __builtin_amdgcn_fdot2(e0, w1, h01, false);                      \
      h02 = __builtin_amdgcn_fdot2(e0, w2, h02, false);                      \
      h03 = __builtin_amdgcn_fdot2(e0, w3, h03, false);                      \
      h10 = __builtin_amdgcn_fdot2(e1, w0, h10, false);                      \
      h11 = __builtin_amdgcn_fdot2(e1, w1, h11, false);                      \
      h12 = __builtin_amdgcn_fdot2(e1, w2, h12, false);                      \
      h13 = __builtin_amdgcn_fdot2(e1, w3, h13, false);                      \
    }                                                                        \
    h00 = fmaxf(h00, 0.2f*h00) * at.x;                                       \
    h01 = fmaxf(h01, 0.2f*h01) * at.y;                                       \
    h02 = fmaxf(h02, 0.2f*h02) * at.z;                                       \
    h03 = fmaxf(h03, 0.2f*h03) * at.w;                                       \
    h10 = fmaxf(h10, 0.2f*h10) * at.x;                                       \
    h11 = fmaxf(h11, 0.2f*h11) * at.y;                                       \
    h12 = fmaxf(h12, 0.2f*h12) * at.z;                                       \
    h13 = fmaxf(h13, 0.2f*h13) * at.w;                                       \
    float g0 = (h00 + h01) + (h02 + h03);                                    \
    float g1 = (h10 + h11) + (h12 + h13);                                    \
    _Pragma("unroll")                                                        \
    for (int off = 1; off < 16; off <<= 1){                                  \
      g0 += __shfl_xor(g0, off);                                             \
      g1 += __shfl_xor(g1, off);                                             \
    }                                                                        \
    float p0 = (P0MASK) ? __expf(g0) : 0.f;                                  \
    float p1 = (V1OK) ? __expf(g1) : 0.f;                                    \
    s += p0 + p1;                                                            \
    a0 = fmaf(p0, x0, fmaf(p1, y0, a0));                                     \
    a1 = fmaf(p0, x1, fmaf(p1, y1, a1));                                     \
    a2 = fmaf(p0, x2, fmaf(p1, y2, a2));                                     \
    a3 = fmaf(p0, x3, fmaf(p1, y3, a3));                                     \
  }
#else
typedef float evt_t;
__device__ __forceinline__ float evload(const float* __restrict__ ea, int e, int l){
  return ea[(size_t)e*EAD + (l & 15)];
}
#define GAT_PAIR(X0, X1, EV0, EV1, V1OK, P0MASK)                             \
  {                                                                          \
    float x0 = b2f(X0.x), x1 = b2f(X0.y), x2 = b2f(X0.z), x3 = b2f(X0.w);    \
    float y0 = b2f(X1.x), y1 = b2f(X1.y), y2 = b2f(X1.z), y3 = b2f(X1.w);    \
    float h00 = x0 + r0, h01 = x1 + r1, h02 = x2 + r2, h03 = x3 + r3;        \
    float h10 = y0 + r0, h11 = y1 + r1, h12 = y2 + r2, h13 = y3 + r3;        \
    int ia0 = __float_as_int(EV0);                                           \
    int ia1 = __float_as_int(EV1);                                           \
    _Pragma("unroll")                                                        \
    for (int k = 0; k < EAD; ++k){                                           \
      float c0 = __int_as_float(__builtin_amdgcn_readlane(ia0, k));          \
      float c1 = __int_as_float(__builtin_amdgcn_readlane(ia1, k));          \
      float4 wv = *(const float4*)&sWeH[k*CW + 4*l];                         \
      h00 = fmaf(c0, wv.x, h00); h01 = fmaf(c0, wv.y, h01);                  \
      h02 = fmaf(c0, wv.z, h02); h03 = fmaf(c0, wv.w, h03);                  \
      h10 = fmaf(c1, wv.x, h10); h11 = fmaf(c1, wv.y, h11);                  \
      h12 = fmaf(c1, wv.z, h12); h13 = fmaf(c1, wv.w, h13);                  \
    }                                                                        \
    h00 = fmaxf(h00, 0.2f*h00) * at.x;                                       \
    h01 = fmaxf(h01, 0.2f*h01) * at.y;                                       \
    h02 = fmaxf(h02, 0.2f*h02) * at.z;                                       \
    h03 = fmaxf(h03, 0.2f*h03) * at.w;                                       \
    h10 = fmaxf(h10, 0.2f*h10) * at.x;                                       \
    h11 = fmaxf(h11, 0.2f*h11) * at.y;                                       \
    h12 = fmaxf(h12, 0.2f*h12) * at.z;                                       \
    h13 = fmaxf(h13, 0.2f*h13) * at.w;                                       \
    float g0 = (h00 + h01) + (h02 + h03);                                    \
    float g1 = (h10 + h11) + (h12 + h13);                                    \
    _Pragma("unroll")                                                        \
    for (int off = 1; off < 16; off <<= 1){                                  \
      g0 += __shfl_xor(g0, off);                                             \
      g1 += __shfl_xor(g1, off);                                             \
    }                                                                        \
    float p0 = (P0MASK) ? __expf(g0) : 0.f;                                  \
    float p1 = (V1OK) ? __expf(g1) : 0.f;                                    \
    s += p0 + p1;                                                            \
    a0 = fmaf(p0, x0, fmaf(p1, y0, a0));                                     \
    a1 = fmaf(p0, x1, fmaf(p1, y1, a1));                                     \
    a2 = fmaf(p0, x2, fmaf(p1, y2, a2));                                     \
    a3 = fmaf(p0, x3, fmaf(p1, y3, a3));                                     \
  }
#endif

// ---------------------------------------------------------------------------
// Merged fused GATv2, BOTH directions + ea colsum + h colsum epilogue.
// R5-proven structure: 2-pair rotation-free double buffer, high occupancy.
// ---------------------------------------------------------------------------
__global__ __launch_bounds__(256)
void gat2_kernel(const unsigned short* __restrict__ xlA_, const unsigned short* __restrict__ xrA_,
                 const float* __restrict__ WeA, const float* __restrict__ attA,
                 const float* __restrict__ biasA, const int2* __restrict__ csrA_,
                 const int* __restrict__ rsA_, float* __restrict__ houtA,
                 const unsigned short* __restrict__ xlB_, const unsigned short* __restrict__ xrB_,
                 const float* __restrict__ WeB, const float* __restrict__ attB,
                 const float* __restrict__ biasB, const int2* __restrict__ csrB_,
                 const int* __restrict__ rsB_, float* __restrict__ houtB,
                 const float* __restrict__ ea, float* __restrict__ mvec, int gsplit)
{
#if HAVE_DOT2
  __shared__ int sWeH[8*CW];     // [kpair][col] packed (We[2k][c], We[2k+1][c])
#else
  __shared__ float sWeH[16*CW];  // f32 We tile
#endif
  __shared__ float csum[4][16][4];
  int t = threadIdx.x, l = t & 63;
  int b = blockIdx.x;
  if (b < NEACOL){
    colsum_seg(b, NEACOL, (const float4*)ea, (long)NEDGE*EAD/4, 4,
               mvec + 128, 1.f/NEDGE, &csum[0][0][0]);
    return;
  }
  b -= NEACOL;
  int ngat = (int)gridDim.x - NEACOL;
  bool isA = b < gsplit;
  const unsigned short* xl = isA ? xlA_ : xlB_;
  const unsigned short* xr = isA ? xrA_ : xrB_;
  const float* We   = isA ? WeA   : WeB;
  const float* att  = isA ? attA  : attB;
  const float* bias = isA ? biasA : biasB;
  const int2* csr   = isA ? csrA_ : csrB_;
  const int* row_start = isA ? rsA_ : rsB_;
  float* hout = isA ? houtA : houtB;
  int ndst = isA ? NB : NP;
  int bid  = isA ? b : b - gsplit;
  int nblk = isA ? gsplit : ngat - gsplit;

#if HAVE_DOT2
  for (int i = t; i < 8*CW; i += 256){
    int j = i >> 8, c = i & 255;
    sWeH[i] = __builtin_bit_cast(int,
        __builtin_amdgcn_cvt_pkrtz(We[(2*j)*CW + c], We[(2*j+1)*CW + c]));
  }
#else
  for (int i = t*4; i < 16*CW; i += 1024)
    *(float4*)&sWeH[i] = *(const float4*)&We[i];
#endif
  __syncthreads();
#if HAVE_DOT2
  // hoist per-lane We columns to registers (loop-invariant, 32 VGPRs)
  int4 wreg[8];
  #pragma unroll
  for (int j = 0; j < 8; ++j) wreg[j] = *(const int4*)&sWeH[j*CW + 4*l];
#endif
  float4 at = *(const float4*)&att[4*l];
  float4 bi = *(const float4*)&bias[(l & 15)*4];
  float cs0 = 0.f, cs1 = 0.f, cs2 = 0.f, cs3 = 0.f;   // column-sum of outputs
  int wid = bid*4 + (t >> 6);
  int nw = nblk*4;
  for (int d = wid; d < ndst; d += nw){
    ushort4 ru = *(const ushort4*)(xr + (size_t)d*CW + 4*l);
    float r0 = b2f(ru.x), r1 = b2f(ru.y), r2 = b2f(ru.z), r3 = b2f(ru.w);
    int rs = row_start[d], re = row_start[d+1];
    float s = 0.f;
    float a0 = 0.f, a1 = 0.f, a2 = 0.f, a3 = 0.f;
    if (rs < re){
      int last = re - 1;
      #define CLMP(x) ((x) > last ? last : (x))
      int2 qA0 = csr[rs],         qA1 = csr[CLMP(rs+1)];
      int2 qB0 = csr[CLMP(rs+2)], qB1 = csr[CLMP(rs+3)];
      int2 nA0 = csr[CLMP(rs+4)], nA1 = csr[CLMP(rs+5)];
      int2 nB0 = csr[CLMP(rs+6)], nB1 = csr[CLMP(rs+7)];
      ushort4 xA0 = *(const ushort4*)(xl + (size_t)qA0.y*CW + 4*l);
      ushort4 xA1 = *(const ushort4*)(xl + (size_t)qA1.y*CW + 4*l);
      evt_t  evA0 = evload(ea, qA0.x, l);
      evt_t  evA1 = evload(ea, qA1.x, l);
      ushort4 xB0 = *(const ushort4*)(xl + (size_t)qB0.y*CW + 4*l);
      ushort4 xB1 = *(const ushort4*)(xl + (size_t)qB1.y*CW + 4*l);
      evt_t  evB0 = evload(ea, qB0.x, l);
      evt_t  evB1 = evload(ea, qB1.x, l);
      for (int i = rs; i < re; i += 4){
        int2 mA0 = csr[CLMP(i+8)],  mA1 = csr[CLMP(i+9)];
        int2 mB0 = csr[CLMP(i+10)], mB1 = csr[CLMP(i+11)];
        GAT_PAIR(xA0, xA1, evA0, evA1, (i+1 < re), true);
        xA0 = *(const ushort4*)(xl + (size_t)nA0.y*CW + 4*l);
        xA1 = *(const ushort4*)(xl + (size_t)nA1.y*CW + 4*l);
        evA0 = evload(ea, nA0.x, l);
        evA1 = evload(ea, nA1.x, l);
        nA0 = mA0; nA1 = mA1;
        GAT_PAIR(xB0, xB1, evB0, evB1, (i+3 < re), (i+2 < re));
        xB0 = *(const ushort4*)(xl + (size_t)nB0.y*CW + 4*l);
        xB1 = *(const ushort4*)(xl + (size_t)nB1.y*CW + 4*l);
        evB0 = evload(ea, nB0.x, l);
        evB1 = evload(ea, nB1.x, l);
        nB0 = mB0; nB1 = mB1;
      }
      #undef CLMP
    }
    float inv = 1.f / (s + 1e-16f);
    float v0 = a0*inv, v1 = a1*inv, v2 = a2*inv, v3 = a3*inv;
    v0 += __shfl_xor(v0, 16); v1 += __shfl_xor(v1, 16);
    v2 += __shfl_xor(v2, 16); v3 += __shfl_xor(v3, 16);
    v0 += __shfl_xor(v0, 32); v1 += __shfl_xor(v1, 32);
    v2 += __shfl_xor(v2, 32); v3 += __shfl_xor(v3, 32);
    if (l < 16){
      float4 o;
      o.x = geluf(v0*0.25f + bi.x);
      o.y = geluf(v1*0.25f + bi.y);
      o.z = geluf(v2*0.25f + bi.z);
      o.w = geluf(v3*0.25f + bi.w);
      *(float4*)(hout + (size_t)d*HID + 4*l) = o;
      cs0 += o.x; cs1 += o.y; cs2 += o.z; cs3 += o.w;
    }
  }
  // block-level column-sum reduce -> one atomic per column (64 per block)
  int w = t >> 6;
  if (l < 16){
    csum[w][l][0] = cs0; csum[w][l][1] = cs1;
    csum[w][l][2] = cs2; csum[w][l][3] = cs3;
  }
  __syncthreads();
  if (t < 64){
    int lq = t >> 2, j = t & 3;
    float sum = csum[0][lq][j] + csum[1][lq][j] + csum[2][lq][j] + csum[3][lq][j];
    float scale = isA ? (1.f/NB) : (1.f/NP);
    float* dst = isA ? (mvec + 64) : mvec;
    atomicAdd(&dst[t], sum * scale);
  }
}

// ---------------------------------------------------------------------------
// k3: token-gather GEMM only (tokb = concat(hp,hb,ea)[eids] @ Wet + bet).
// ---------------------------------------------------------------------------
__device__ void gemmcat_body(int bid, const float* __restrict__ hp, const float* __restrict__ hb,
                             const float* __restrict__ ea, const int* __restrict__ esrc,
                             const int* __restrict__ edst, const int* __restrict__ eids,
                             const float* __restrict__ W, const float* __restrict__ bias,
                             float* __restrict__ out)
{
  __shared__ float sAT[16][68];
  __shared__ float sB[16][68];
  __shared__ int sS[64], sD[64], sE[64];
  int t = threadIdx.x;
  int m0 = (bid >> 1)*64, n0 = (bid & 1)*64;
  if (t < 64){
    int e = eids[m0 + t];
    sS[t] = esrc[e]; sD[t] = edst[e]; sE[t] = e;
  }
  __syncthreads();
  int tr = t >> 4, tc = t & 15;
  float acc[4][4] = {};
  for (int k0 = 0; k0 < 144; k0 += 16){
    {
      int r = t >> 2, c = (t & 3) * 4;
      const float* src; int col = k0 + c;
      if (k0 < 64)       { src = hp + (size_t)sS[r]*HID; }
      else if (k0 < 128) { src = hb + (size_t)sD[r]*HID; col -= 64; }
      else               { src = ea + (size_t)sE[r]*EAD; col -= 128; }
      float4 va = *(const float4*)(src + col);
      sAT[c+0][r] = va.x; sAT[c+1][r] = va.y; sAT[c+2][r] = va.z; sAT[c+3][r] = va.w;
    }
    {
      int r = t >> 4, c = (t & 15) * 4;
      float4 vb = *(const float4*)(W + (size_t)(k0+r)*DD + n0 + c);
      *(float4*)&sB[r][c] = vb;
    }
    __syncthreads();
    #pragma unroll
    for (int k = 0; k < 16; ++k){
      float4 av = *(const float4*)&sAT[k][tr*4];
      float4 bv = *(const float4*)&sB[k][tc*4];
      acc[0][0] = fmaf(av.x, bv.x, acc[0][0]);
      acc[0][1] = fmaf(av.x, bv.y, acc[0][1]);
      acc[0][2] = fmaf(av.x, bv.z, acc[0][2]);
      acc[0][3] = fmaf(av.x, bv.w, acc[0][3]);
      acc[1][0] = fmaf(av.y, bv.x, acc[1][0]);
      acc[1][1] = fmaf(av.y, bv.y, acc[1][1]);
      acc[1][2] = fmaf(av.y, bv.z, acc[1][2]);
      acc[1][3] = fmaf(av.y, bv.w, acc[1][3]);
      acc[2][0] = fmaf(av.z, bv.x, acc[2][0]);
      acc[2][1] = fmaf(av.z, bv.y, acc[2][1]);
      acc[2][2] = fmaf(av.z, bv.z, acc[2][2]);
      acc[2][3] = fmaf(av.z, bv.w, acc[2][3]);
      acc[3][0] = fmaf(av.w, bv.x, acc[3][0]);
      acc[3][1] = fmaf(av.w, bv.y, acc[3][1]);
      acc[3][2] = fmaf(av.w, bv.z, acc[3][2]);
      acc[3][3] = fmaf(av.w, bv.w, acc[3][3]);
    }
    __syncthreads();
  }
  #pragma unroll
  for (int i = 0; i < 4; ++i){
    int gr = m0 + tr*4 + i;
    float4 v;
    v.x = acc[i][0] + bias[n0 + tc*4 + 0];
    v.y = acc[i][1] + bias[n0 + tc*4 + 1];
    v.z = acc[i][2] + bias[n0 + tc*4 + 2];
    v.w = acc[i][3] + bias[n0 + tc*4 + 3];
    *(float4*)(out + (size_t)gr*DD + n0 + tc*4) = v;
  }
}

__global__ __launch_bounds__(256)
void gemmcat_kernel(const float* __restrict__ hp, const float* __restrict__ hb,
                    const float* __restrict__ ea, const int* __restrict__ esrc,
                    const int* __restrict__ edst, const int* __restrict__ eids,
                    const float* __restrict__ Wet, const float* __restrict__ bet,
                    float* __restrict__ tokb)
{
  gemmcat_body(blockIdx.x, hp, hb, ea, esrc, edst, eids, Wet, bet, tokb);
}

// ---------------------------------------------------------------------------
// qstageF: one (column-quad q, k-chunk ch) unit of a 6-row GEMM stage.
// ---------------------------------------------------------------------------
template<int K, int N, int NC>
__device__ __forceinline__ void qstageF(const float* __restrict__ x,
                                        const float* __restrict__ W,
                                        float (&a)[6][4], int q, int ch)
{
  constexpr int NQ = N/4;
  constexpr int KC = K/NC;     // multiple of 4
  constexpr int J  = KC/4;     // power of 2
  const float4* wp = (const float4*)W + (size_t)(ch*KC)*NQ + q;
  const float* xb = x + ch*KC;
  float4 wv[KC];
  int kx[J];
  #pragma unroll
  for (int j = 0; j < J; ++j){
    int k4 = (j + ch) & (J-1);
    kx[j] = k4;
    wv[j*4+0] = wp[(size_t)(k4*4+0)*NQ];
    wv[j*4+1] = wp[(size_t)(k4*4+1)*NQ];
    wv[j*4+2] = wp[(size_t)(k4*4+2)*NQ];
    wv[j*4+3] = wp[(size_t)(k4*4+3)*NQ];
  }
  #pragma unroll
  for (int s = 0; s < 6; ++s){ a[s][0]=0.f; a[s][1]=0.f; a[s][2]=0.f; a[s][3]=0.f; }
  #pragma unroll
  for (int j = 0; j < J; ++j){
    #pragma unroll
    for (int s = 0; s < 6; ++s){
      float4 xv = *(const float4*)&xb[s*K + kx[j]*4];
      a[s][0]=fmaf(xv.x,wv[j*4+0].x,a[s][0]); a[s][0]=fmaf(xv.y,wv[j*4+1].x,a[s][0]);
      a[s][0]=fmaf(xv.z,wv[j*4+2].x,a[s][0]); a[s][0]=fmaf(xv.w,wv[j*4+3].x,a[s][0]);
      a[s][1]=fmaf(xv.x,wv[j*4+0].y,a[s][1]); a[s][1]=fmaf(xv.y,wv[j*4+1].y,a[s][1]);
      a[s][1]=fmaf(xv.z,wv[j*4+2].y,a[s][1]); a[s][1]=fmaf(xv.w,wv[j*4+3].y,a[s][1]);
      a[s][2]=fmaf(xv.x,wv[j*4+0].z,a[s][2]); a[s][2]=fmaf(xv.y,wv[j*4+1].z,a[s][2]);
      a[s][2]=fmaf(xv.z,wv[j*4+2].z,a[s][2]); a[s][2]=fmaf(xv.w,wv[j*4+3].z,a[s][2]);
      a[s][3]=fmaf(xv.x,wv[j*4+0].w,a[s][3]); a[s][3]=fmaf(xv.y,wv[j*4+1].w,a[s][3]);
      a[s][3]=fmaf(xv.z,wv[j*4+2].w,a[s][3]); a[s][3]=fmaf(xv.w,wv[j*4+3].w,a[s][3]);
    }
  }
  #pragma unroll
  for (int off = 1; off < NC; off <<= 1){
    #pragma unroll
    for (int s = 0; s < 6; ++s){
      a[s][0]+=__shfl_xor(a[s][0],off); a[s][1]+=__shfl_xor(a[s][1],off);
      a[s][2]+=__shfl_xor(a[s][2],off); a[s][3]+=__shfl_xor(a[s][3],off);
    }
  }
}

// ---------------------------------------------------------------------------
// Fused transformer: buildx + 2 encoder layers + ctxdot in ONE block (512 thr).
// ---------------------------------------------------------------------------
__global__ __launch_bounds__(512)
void xform_kernel(const float* __restrict__ hist, const float* __restrict__ mvec,
                  const float* __restrict__ Wgs, const float* __restrict__ bgs,
                  const float* __restrict__ pos,
                  const float* __restrict__ Wqkv, const float* __restrict__ bqkv,
                  const float* __restrict__ Wo, const float* __restrict__ bo,
                  const float* __restrict__ ln1g, const float* __restrict__ ln1b,
                  const float* __restrict__ W1, const float* __restrict__ b1,
                  const float* __restrict__ W2, const float* __restrict__ b2,
                  const float* __restrict__ ln2g, const float* __restrict__ ln2b,
                  const float* __restrict__ Wc1, const float* __restrict__ bc1,
                  float* __restrict__ bias2)
{
  __shared__ float sx[SEQ*DD];       // current x
  __shared__ float sq[SEQ*3*DD];     // qkv
  __shared__ float sh[SEQ*512];      // ffn hidden / pre-LN1 buffer
  __shared__ float st[SEQ*DD];       // attn-out / pre-LN2 buffer
  __shared__ float sc[4][6][6];
  __shared__ float smv[144];
  int t = threadIdx.x;

  // rows 0..4 = hist+pos ; mvec -> LDS
  for (int i = t; i < (SEQ-1)*DD; i += 512) sx[i] = hist[i] + pos[i];
  if (t < 144) smv[t] = mvec[t];
  __syncthreads();
  // row 5 = mvec @ Wgs + bgs + pos[5]   (32 quads x 8 chunks of 18 k)
  if (t < 256){
    int q = t >> 3, ch = t & 7;
    float4 wv[18];
    #pragma unroll
    for (int kk = 0; kk < 18; ++kk)
      wv[kk] = *(const float4*)&Wgs[(ch*18+kk)*DD + q*4];
    float a0=0.f,a1=0.f,a2=0.f,a3=0.f;
    #pragma unroll
    for (int kk = 0; kk < 18; ++kk){
      float xv = smv[ch*18+kk];
      a0=fmaf(xv,wv[kk].x,a0); a1=fmaf(xv,wv[kk].y,a1);
      a2=fmaf(xv,wv[kk].z,a2); a3=fmaf(xv,wv[kk].w,a3);
    }
    #pragma unroll
    for (int off = 1; off < 8; off <<= 1){
      a0+=__shfl_xor(a0,off); a1+=__shfl_xor(a1,off);
      a2+=__shfl_xor(a2,off); a3+=__shfl_xor(a3,off);
    }
    if (ch == 0){
      int n = q*4, base = (SEQ-1)*DD + n;
      sx[base+0]=a0+bgs[n+0]+pos[base+0];
      sx[base+1]=a1+bgs[n+1]+pos[base+1];
      sx[base+2]=a2+bgs[n+2]+pos[base+2];
      sx[base+3]=a3+bgs[n+3]+pos[base+3];
    }
  }
  __syncthreads();

  for (int lyr = 0; lyr < L; ++lyr){
    // qkv = x @ Wqkv + bqkv   (96 quads x NC=4 chunks = 384 units, 32 loads ea)
    if (t < 384){
      int q = t >> 2, ch = t & 3;
      const float* wq = Wqkv + (size_t)lyr*DD*3*DD;
      const float* bq = bqkv + lyr*3*DD;
      float a[6][4];
      qstageF<128,384,4>(sx, wq, a, q, ch);
      if (ch == 0){
        int n = q*4;
        #pragma unroll
        for (int s = 0; s < 6; ++s){
          sq[s*384+n+0]=a[s][0]+bq[n+0];
          sq[s*384+n+1]=a[s][1]+bq[n+1];
          sq[s*384+n+2]=a[s][2]+bq[n+2];
          sq[s*384+n+3]=a[s][3]+bq[n+3];
        }
      }
    }
    __syncthreads();
    // scores
    if (t < 144){
      int h = t/36, r = t%36, qi = r/6, ki = r%6;
      float acc = 0.f;
      #pragma unroll
      for (int d2 = 0; d2 < 32; ++d2)
        acc = fmaf(sq[qi*384 + h*32 + d2], sq[ki*384 + 128 + h*32 + d2], acc);
      sc[h][qi][ki] = acc * 0.17677669529663687f;
    }
    __syncthreads();
    if (t < 24){
      int h = t/6, qi = t%6;
      float* row = sc[h][qi];
      float mx = row[0];
      #pragma unroll
      for (int k = 1; k < 6; ++k) mx = fmaxf(mx, row[k]);
      float sm = 0.f;
      #pragma unroll
      for (int k = 0; k < 6; ++k){ row[k] = __expf(row[k]-mx); sm += row[k]; }
      float inv = 1.f/sm;
      #pragma unroll
      for (int k = 0; k < 6; ++k) row[k] *= inv;
    }
    __syncthreads();
    // attention output -> st
    for (int i = t; i < SEQ*DD; i += 512){
      int s = i >> 7, n = i & 127, h = n >> 5, d2 = n & 31;
      float acc = 0.f;
      #pragma unroll
      for (int ki = 0; ki < 6; ++ki)
        acc = fmaf(sc[h][s][ki], sq[ki*384 + 256 + h*32 + d2], acc);
      st[i] = acc;
    }
    __syncthreads();
    // proj: st @ Wo + bo + resid(sx) -> sh   (32 quads x NC=16 = 512 units, 8 loads)
    {
      int q = t >> 4, ch = t & 15;
      float a[6][4];
      qstageF<128,128,16>(st, Wo + (size_t)lyr*DD*DD, a, q, ch);
      if (ch == 0){
        int n = q*4;
        const float* bop = bo + lyr*DD;
        #pragma unroll
        for (int s = 0; s < 6; ++s){
          sh[s*128+n+0]=a[s][0]+bop[n+0]+sx[s*128+n+0];
          sh[s*128+n+1]=a[s][1]+bop[n+1]+sx[s*128+n+1];
          sh[s*128+n+2]=a[s][2]+bop[n+2]+sx[s*128+n+2];
          sh[s*128+n+3]=a[s][3]+bop[n+3]+sx[s*128+n+3];
        }
      }
    }
    __syncthreads();
    // LN1 (single phase): sh -> sx, one wave per row
    {
      int w = t >> 6, lw = t & 63;
      if (w < SEQ){
        const float* g = ln1g + lyr*DD; const float* be = ln1b + lyr*DD;
        float v0 = sh[w*DD + lw], v1 = sh[w*DD + 64 + lw];
        float sm = v0 + v1;
        #pragma unroll
        for (int off = 1; off < 64; off <<= 1) sm += __shfl_xor(sm, off);
        float mean = sm * 0.0078125f;
        float d0 = v0-mean, d1 = v1-mean;
        float qv = d0*d0 + d1*d1;
        #pragma unroll
        for (int off = 1; off < 64; off <<= 1) qv += __shfl_xor(qv, off);
        float inv = rsqrtf(qv*0.0078125f + 1e-5f);
        sx[w*DD + lw]      = d0*inv*g[lw] + be[lw];
        sx[w*DD + 64 + lw] = d1*inv*g[64+lw] + be[64+lw];
      }
    }
    __syncthreads();
    // ffn1: sx @ W1 -> gelu -> sh[6][512]   (128 quads x NC=4 = 512 units, 32 loads)
    {
      int q = t >> 2, ch = t & 3;
      const float* w1 = W1 + (size_t)lyr*DD*512;
      const float* b1p = b1 + lyr*512;
      float a[6][4];
      qstageF<128,512,4>(sx, w1, a, q, ch);
      if (ch == 0){
        int n = q*4;
        #pragma unroll
        for (int s = 0; s < 6; ++s){
          sh[s*512+n+0]=geluf(a[s][0]+b1p[n+0]);
          sh[s*512+n+1]=geluf(a[s][1]+b1p[n+1]);
          sh[s*512+n+2]=geluf(a[s][2]+b1p[n+2]);
          sh[s*512+n+3]=geluf(a[s][3]+b1p[n+3]);
        }
      }
    }
    __syncthreads();
    // ffn2: sh @ W2 + b2 + resid(sx) -> st   (32 quads x NC=16 = 512 units, 32 loads)
    {
      int q = t >> 4, ch = t & 15;
      const float* w2 = W2 + (size_t)lyr*512*DD;
      const float* b2p = b2 + lyr*DD;
      float a[6][4];
      qstageF<512,128,16>(sh, w2, a, q, ch);
      if (ch == 0){
        int n = q*4;
        #pragma unroll
        for (int s = 0; s < 6; ++s){
          st[s*128+n+0]=a[s][0]+b2p[n+0]+sx[s*128+n+0];
          st[s*128+n+1]=a[s][1]+b2p[n+1]+sx[s*128+n+1];
          st[s*128+n+2]=a[s][2]+b2p[n+2]+sx[s*128+n+2];
          st[s*128+n+3]=a[s][3]+b2p[n+3]+sx[s*128+n+3];
        }
      }
    }
    __syncthreads();
    // LN2 (single phase): st -> sx
    {
      int w = t >> 6, lw = t & 63;
      if (w < SEQ){
        const float* g = ln2g + lyr*DD; const float* be = ln2b + lyr*DD;
        float v0 = st[w*DD + lw], v1 = st[w*DD + 64 + lw];
        float sm = v0 + v1;
        #pragma unroll
        for (int off = 1; off < 64; off <<= 1) sm += __shfl_xor(sm, off);
        float mean = sm * 0.0078125f;
        float d0 = v0-mean, d1 = v1-mean;
        float qv = d0*d0 + d1*d1;
        #pragma unroll
        for (int off = 1; off < 64; off <<= 1) qv += __shfl_xor(qv, off);
        float inv = rsqrtf(qv*0.0078125f + 1e-5f);
        sx[w*DD + lw]      = d0*inv*g[lw] + be[lw];
        sx[w*DD + 64 + lw] = d1*inv*g[64+lw] + be[64+lw];
      }
    }
    __syncthreads();
  }
  // ctxdot: bias2[n] = bc1[n] + sum_k ctx[k]*Wc1[128+k][n]  (32 quads x 8 chunks)
  if (t < 256){
    int q = t >> 3, ch = t & 7;
    const float4* wp = (const float4*)(Wc1 + (size_t)DD*DD) + (size_t)(ch*16)*32 + q;
    const float* xb = &sx[(SEQ-1)*DD + ch*16];
    float4 wv[16];
    int kx[4];
    #pragma unroll
    for (int j = 0; j < 4; ++j){
      int k4 = (j + ch) & 3;
      kx[j] = k4;
      wv[j*4+0] = wp[(size_t)(k4*4+0)*32];
      wv[j*4+1] = wp[(size_t)(k4*4+1)*32];
      wv[j*4+2] = wp[(size_t)(k4*4+2)*32];
      wv[j*4+3] = wp[(size_t)(k4*4+3)*32];
    }
    float a0=0.f,a1=0.f,a2=0.f,a3=0.f;
    #pragma unroll
    for (int j = 0; j < 4; ++j){
      float4 xv = *(const float4*)&xb[kx[j]*4];
      a0=fmaf(xv.x,wv[j*4+0].x,a0); a0=fmaf(xv.y,wv[j*4+1].x,a0);
      a0=fmaf(xv.z,wv[j*4+2].x,a0); a0=fmaf(xv.w,wv[j*4+3].x,a0);
      a1=fmaf(xv.x,wv[j*4+0].y,a1); a1=fmaf(xv.y,wv[j*4+1].y,a1);
      a1=fmaf(xv.z,wv[j*4+2].y,a1); a1=fmaf(xv.w,wv[j*4+3].y,a1);
      a2=fmaf(xv.x,wv[j*4+0].z,a2); a2=fmaf(xv.y,wv[j*4+1].z,a2);
      a2=fmaf(xv.z,wv[j*4+2].z,a2); a2=fmaf(xv.w,wv[j*4+3].z,a2);
      a3=fmaf(xv.x,wv[j*4+0].w,a3); a3=fmaf(xv.y,wv[j*4+1].w,a3);
      a3=fmaf(xv.z,wv[j*4+2].w,a3); a3=fmaf(xv.w,wv[j*4+3].w,a3);
    }
    #pragma unroll
    for (int off = 1; off < 8; off <<= 1){
      a0+=__shfl_xor(a0,off); a1+=__shfl_xor(a1,off);
      a2+=__shfl_xor(a2,off); a3+=__shfl_xor(a3,off);
    }
    if (ch == 0){
      int n = q*4;
      bias2[n+0]=a0+bc1[n+0];
      bias2[n+1]=a1+bc1[n+1];
      bias2[n+2]=a2+bc1[n+2];
      bias2[n+3]=a3+bc1[n+3];
    }
  }
}

// ---------------------------------------------------------------------------
// cls: fused hid = gelu(tokb @ Wc1[0:128] + bias2) ; out = hid @ Wc2 + bc2.
// ---------------------------------------------------------------------------
__global__ __launch_bounds__(256)
void cls_kernel(const float* __restrict__ A, const float* __restrict__ W,
                const float* __restrict__ bias2, const float* __restrict__ Wc2,
                const float* __restrict__ bc2, float* __restrict__ out)
{
  __shared__ float sAT[16][68];
  __shared__ float sB[16][132];
  __shared__ float sH[64][129];
  int t = threadIdx.x;
  int m0 = blockIdx.x * 64;
  int tr = t >> 4, tc = t & 15;
  float acc[4][8] = {};
  for (int k0 = 0; k0 < DD; k0 += 16){
    {
      int r = t >> 2, c = (t & 3) * 4;
      float4 va = *(const float4*)(A + (size_t)(m0+r)*DD + k0 + c);
      sAT[c+0][r] = va.x; sAT[c+1][r] = va.y; sAT[c+2][r] = va.z; sAT[c+3][r] = va.w;
    }
    {
      int r = t >> 4, c = (t & 15) * 8;
      float4 b0 = *(const float4*)(W + (size_t)(k0+r)*DD + c);
      float4 b1 = *(const float4*)(W + (size_t)(k0+r)*DD + c + 4);
      *(float4*)&sB[r][c] = b0;
      *(float4*)&sB[r][c+4] = b1;
    }
    __syncthreads();
    #pragma unroll
    for (int k = 0; k < 16; ++k){
      float4 av = *(const float4*)&sAT[k][tr*4];
      float4 b0 = *(const float4*)&sB[k][tc*8];
      float4 b1 = *(const float4*)&sB[k][tc*8+4];
      #pragma unroll
      for (int i = 0; i < 4; ++i){
        float avi = (i==0)?av.x:(i==1)?av.y:(i==2)?av.z:av.w;
        acc[i][0] = fmaf(avi, b0.x, acc[i][0]);
        acc[i][1] = fmaf(avi, b0.y, acc[i][1]);
        acc[i][2] = fmaf(avi, b0.z, acc[i][2]);
        acc[i][3] = fmaf(avi, b0.w, acc[i][3]);
        acc[i][4] = fmaf(avi, b1.x, acc[i][4]);
        acc[i][5] = fmaf(avi, b1.y, acc[i][5]);
        acc[i][6] = fmaf(avi, b1.z, acc[i][6]);
        acc[i][7] = fmaf(avi, b1.w, acc[i][7]);
      }
    }
    __syncthreads();
  }
  // epilogue: gelu(acc + bias2) -> sH
  #pragma unroll
  for (int i = 0; i < 4; ++i){
    #pragma unroll
    for (int j = 0; j < 8; ++j){
      sH[tr*4+i][tc*8+j] = geluf(acc[i][j] + bias2[tc*8+j]);
    }
  }
  __syncthreads();
  // head: out[m0+row][c] = sH[row] . Wc2[:,c] + bc2[c]
  if (t < 64){
    float a10[NCLS];
    #pragma unroll
    for (int c = 0; c < NCLS; ++c) a10[c] = bc2[c];
    for (int k = 0; k < DD; ++k){
      float hv = sH[t][k];
      #pragma unroll
      for (int c = 0; c < NCLS; ++c)
        a10[c] = fmaf(hv, Wc2[k*NCLS + c], a10[c]);
    }
    #pragma unroll
    for (int c = 0; c < NCLS; ++c)
      out[(size_t)(m0+t)*NCLS + c] = a10[c];
  }
}

extern "C" void kernel_launch(void* const* d_in, const int* in_sizes, int n_in,
                              void* d_out, int out_size, void* d_ws, size_t ws_size,
                              hipStream_t stream){
  (void)in_sizes; (void)n_in; (void)out_size; (void)ws_size;
  const float* pitcher = (const float*)d_in[0];
  const float* batter  = (const float*)d_in[1];
  const float* eattr   = (const float*)d_in[2];
  const float* hist    = (const float*)d_in[3];
  const float* Wp = (const float*)d_in[4];
  const float* bp = (const float*)d_in[5];
  const float* Wb = (const float*)d_in[6];
  const float* bb = (const float*)d_in[7];
  const float* rel_Wl  = (const float*)d_in[8];
  const float* rel_bl  = (const float*)d_in[9];
  const float* rel_Wr  = (const float*)d_in[10];
  const float* rel_br  = (const float*)d_in[11];
  const float* rel_We  = (const float*)d_in[12];
  const float* rel_att = (const float*)d_in[13];
  const float* rel_bias= (const float*)d_in[14];
  const float* rev_Wl  = (const float*)d_in[15];
  const float* rev_bl  = (const float*)d_in[16];
  const float* rev_Wr  = (const float*)d_in[17];
  const float* rev_br  = (const float*)d_in[18];
  const float* rev_We  = (const float*)d_in[19];
  const float* rev_att = (const float*)d_in[20];
  const float* rev_bias= (const float*)d_in[21];
  const float* Wgs = (const float*)d_in[22];
  const float* bgs = (const float*)d_in[23];
  const float* Wet = (const float*)d_in[24];
  const float* bet = (const float*)d_in[25];
  const float* pos = (const float*)d_in[26];
  const float* Wqkv= (const float*)d_in[27];
  const float* bqkv= (const float*)d_in[28];
  const float* Wo  = (const float*)d_in[29];
  const float* bo  = (const float*)d_in[30];
  const float* ln1g= (const float*)d_in[31];
  const float* ln1b= (const float*)d_in[32];
  const float* W1  = (const float*)d_in[33];
  const float* b1  = (const float*)d_in[34];
  const float* W2  = (const float*)d_in[35];
  const float* b2  = (const float*)d_in[36];
  const float* ln2g= (const float*)d_in[37];
  const float* ln2b= (const float*)d_in[38];
  const float* Wc1 = (const float*)d_in[39];
  const float* bc1 = (const float*)d_in[40];
  const float* Wc2 = (const float*)d_in[41];
  const float* bc2 = (const float*)d_in[42];
  const int* esrc = (const int*)d_in[43];
  const int* edst = (const int*)d_in[44];
  const int* eids = (const int*)d_in[45];

  // workspace carve-out
  char* w = (char*)d_ws;
  size_t off = 0;
  auto alloc = [&](size_t bytes)->void*{
    void* p = (void*)(w + off);
    off += (bytes + 255) & ~(size_t)255;
    return p;
  };
  unsigned short* px_bf  = (unsigned short*)alloc((size_t)NP*HID*2);
  unsigned short* bx_bf  = (unsigned short*)alloc((size_t)NB*HID*2);
  float*          hp     = (float*)alloc((size_t)NP*HID*4);
  float*          hb     = (float*)alloc((size_t)NB*HID*4);
  unsigned short* xlA    = (unsigned short*)alloc((size_t)NP*CW*2);  // rel: src=pitcher
  unsigned short* xrA    = (unsigned short*)alloc((size_t)NB*CW*2);  // rel: dst=batter
  unsigned short* xlB    = (unsigned short*)alloc((size_t)NB*CW*2);  // rev: src=batter
  unsigned short* xrB    = (unsigned short*)alloc((size_t)NP*CW*2);  // rev: dst=pitcher
  int*            degAB  = (int*)alloc((size_t)(NB+NP)*4);
  int*            degA   = degAB;
  int*            degB   = degAB + NB;
  int*            rowstA = (int*)alloc((size_t)(NB+1)*4);
  int*            rowstB = (int*)alloc((size_t)(NP+1)*4);
  int*            cursA  = (int*)alloc((size_t)NB*4);
  int*            cursB  = (int*)alloc((size_t)NP*4);
  int2*           csrA   = (int2*)alloc((size_t)NEDGE*8);
  int2*           csrB   = (int2*)alloc((size_t)NEDGE*8);
  float*          mvec   = (float*)alloc(144*4);
  float*          bias2  = (float*)alloc(DD*4);
  // alias over dead GAT buffer (xlA dead after gat2):
  float*          tokb   = (float*)xlA;   // BEDGE*DD*4 = 4.19MB <= 5.12MB

  const int nbCount = (NEDGE + 255)/256;          // 1172
  const int nbP = (NP + 63)/64;                   // 157
  const int nbB = (NB + 63)/64;                   // 469

  // k1: degree count (both dirs) || node encoders
  hipMemsetAsync(degAB, 0, (size_t)(NB+NP)*4, stream);
  k1_count_enc<<<nbCount + nbP + nbB, 256, 0, stream>>>(
      edst, esrc, degA, degB,
      pitcher, Wp, bp, px_bf, batter, Wb, bb, bx_bf, nbCount, nbP);

  // scan both CSRs (2 blocks) + zero mvec
  scan2_kernel<<<2, 1024, 0, stream>>>(degA, rowstA, cursA, NB,
                                       degB, rowstB, cursB, NP, mvec);

  // k2: CSR scatter || all four projection GEMMs
  k2_scatter_proj<<<nbCount + 2*nbP + 2*nbB, 256, 0, stream>>>(
      edst, esrc, cursA, cursB, csrA, csrB, px_bf, bx_bf,
      rel_Wl, rel_bl, rel_Wr, rel_br, rev_Wl, rev_bl, rev_Wr, rev_br,
      xlA, xrA, xlB, xrB, nbCount, nbP, nbB);

  // merged GAT (both dirs) + ea colsum + h colsum epilogue
  gat2_kernel<<<NEACOL + 4096, 256, 0, stream>>>(
      xlA, xrA, rel_We, rel_att, rel_bias, csrA, rowstA, hb,
      xlB, xrB, rev_We, rev_att, rev_bias, csrB, rowstB, hp,
      eattr, mvec, 2048);

  // k3: token-gather GEMM (tokb = cat @ Wet + bet)
  gemmcat_kernel<<<256, 256, 0, stream>>>(
      hp, hb, eattr, esrc, edst, eids, Wet, bet, tokb);

  // fused transformer (buildx + 2 layers + ctxdot) -> bias2
  xform_kernel<<<1, 512, 0, stream>>>(
      hist, mvec, Wgs, bgs, pos, Wqkv, bqkv, Wo, bo, ln1g, ln1b,
      W1, b1, W2, b2, ln2g, ln2b, Wc1, bc1, bias2);

  // classifier (hid GEMM + head fused)
  cls_kernel<<<BEDGE/64, 256, 0, stream>>>(tokb, Wc1, bias2, Wc2, bc2, (float*)d_out);
}

// Round 12
// 373.816 us; speedup vs baseline: 1.1134x; 1.0034x over previous
//
#include <hip/hip_runtime.h>
#include <math.h>

// Problem constants (match reference)
#define NP 10000
#define NB 30000
#define NEDGE 300000
#define BEDGE 8192
#define EAD 16
#define HID 64
#define GH 4
#define CW 256      // GH*HID
#define DD 128
#define SEQ 6
#define NCLS 10
#define L 2
#define NEACOL 64   // ea-colsum blocks folded into gat2 grid

#if defined(__has_builtin)
#  if __has_builtin(__builtin_amdgcn_fdot2)
#    define HAVE_DOT2 1
#  else
#    define HAVE_DOT2 0
#  endif
#else
#  define HAVE_DOT2 0
#endif

typedef _Float16 h16x2 __attribute__((ext_vector_type(2)));

__device__ __forceinline__ float geluf(float x){
  // jax.nn.gelu(approximate=False)
  return 0.5f * x * (1.0f + erff(x * 0.7071067811865475f));
}

__device__ __forceinline__ float b2f(unsigned short u){
  unsigned v = ((unsigned)u) << 16;
  return __int_as_float(v);
}
__device__ __forceinline__ unsigned short f2b(float f){
  unsigned x = __float_as_uint(f);
  unsigned r = x + 0x7FFF + ((x >> 16) & 1);   // round-to-nearest-even
  return (unsigned short)(r >> 16);
}

typedef __attribute__((ext_vector_type(8))) short bf16x8;
typedef __attribute__((ext_vector_type(4))) float f32x4;

// ---------------------------------------------------------------------------
// MFMA GEMM body: out_bf16[M][N] = (GELU?)(A[M][KQ] @ W[KQ][N] + bias[N])
// Epilogue routes the C tile through LDS (reusing sWt after a barrier) so
// global stores are coalesced int4 (16B/lane) instead of scalar ushort.
// ---------------------------------------------------------------------------
template<int KQ, int NTILES, bool A_F32, bool GELU>
__device__ __forceinline__
void mfma_gemm_body(int bid, const void* __restrict__ Av, const float* __restrict__ W,
                    const float* __restrict__ bias, unsigned short* __restrict__ out,
                    int M, unsigned short* __restrict__ sWt)
{
  constexpr int N  = NTILES * 16;
  constexpr int KP = KQ + 8;
  constexpr int NP8 = N + 8;     // padded LDS row stride (ushorts), 16B-aligned
  int t = threadIdx.x, w = t >> 6, l = t & 63;
  int c = l & 15, g = l >> 4;
  for (int idx = t; idx < KQ*N; idx += 256){
    int k = idx / N, n = idx - k*N;
    sWt[n*KP + k] = f2b(W[idx]);
  }
  __syncthreads();
  int rowbase = bid*64 + w*16;
  int arow = rowbase + c; if (arow > M-1) arow = M-1;   // clamp (no OOB reads)
  f32x4 acc[NTILES] = {};
  #pragma unroll
  for (int ks = 0; ks < KQ/32; ++ks){
    int koff = ks*32 + g*8;
    bf16x8 a;
    if constexpr (A_F32){
      const float* Af = (const float*)Av + (size_t)arow*KQ + koff;
      float4 f0 = *(const float4*)Af;
      float4 f1 = *(const float4*)(Af + 4);
      a[0]=(short)f2b(f0.x); a[1]=(short)f2b(f0.y); a[2]=(short)f2b(f0.z); a[3]=(short)f2b(f0.w);
      a[4]=(short)f2b(f1.x); a[5]=(short)f2b(f1.y); a[6]=(short)f2b(f1.z); a[7]=(short)f2b(f1.w);
    } else {
      a = *(const bf16x8*)((const unsigned short*)Av + (size_t)arow*KQ + koff);
    }
    #pragma unroll
    for (int nt = 0; nt < NTILES; ++nt){
      bf16x8 b = *(const bf16x8*)&sWt[(nt*16 + c)*KP + koff];
      acc[nt] = __builtin_amdgcn_mfma_f32_16x16x32_bf16(a, b, acc[nt], 0, 0, 0);
    }
  }
  // epilogue: acc -> LDS (bias/gelu/bf16), then coalesced 16B global stores
  __syncthreads();     // all waves done reading sWt
  #pragma unroll
  for (int nt = 0; nt < NTILES; ++nt){
    #pragma unroll
    for (int j = 0; j < 4; ++j){
      float v = acc[nt][j] + bias[nt*16 + c];
      if (GELU) v = geluf(v);
      sWt[(w*16 + g*4 + j)*NP8 + nt*16 + c] = f2b(v);
    }
  }
  __syncthreads();
  int blockrow0 = bid*64;
  constexpr int C8 = N/8;        // 16B chunks per row
  for (int idx = t; idx < 64*C8; idx += 256){
    int row = idx / C8, c8 = idx - row*C8;
    if (blockrow0 + row < M){
      *(int4*)(out + (size_t)(blockrow0 + row)*N + c8*8) =
          *(const int4*)&sWt[row*NP8 + c8*8];
    }
  }
}

// ---------------------------------------------------------------------------
// k1: edge-degree count (both dirs) || node encoders (pitcher+batter) merged.
// ---------------------------------------------------------------------------
__global__ __launch_bounds__(256)
void k1_count_enc(const int* __restrict__ edst, const int* __restrict__ esrc,
                  int* __restrict__ degA, int* __restrict__ degB,
                  const float* __restrict__ pit, const float* __restrict__ Wp,
                  const float* __restrict__ bp, unsigned short* __restrict__ px,
                  const float* __restrict__ bat, const float* __restrict__ Wb,
                  const float* __restrict__ bb, unsigned short* __restrict__ bx,
                  int nbCount, int nbP)
{
  __shared__ unsigned short sWt[64*136];   // N=64, KP=136 (>= 64*72 for epilogue)
  int b = blockIdx.x;
  if (b < nbCount){
    int i = b*256 + threadIdx.x;
    if (i < NEDGE){
      atomicAdd(&degA[edst[i]], 1);
      atomicAdd(&degB[esrc[i]], 1);
    }
  } else if (b < nbCount + nbP){
    mfma_gemm_body<128,4,true,true>(b - nbCount, pit, Wp, bp, px, NP, sWt);
  } else {
    mfma_gemm_body<128,4,true,true>(b - nbCount - nbP, bat, Wb, bb, bx, NB, sWt);
  }
}

// ---------------------------------------------------------------------------
// scan: shuffle-based exclusive scan, 4 elems/thread
// ---------------------------------------------------------------------------
__device__ void scan_dev(const int* __restrict__ deg, int* __restrict__ row_start,
                         int* __restrict__ cursor, int n){
  __shared__ int wsum[16];
  __shared__ int sbase;
  int t = threadIdx.x, w = t >> 6, l = t & 63;
  if (t == 0) sbase = 0;
  __syncthreads();
  for (int base = 0; base < n; base += 4096){
    int i = base + t*4;
    int4 v = make_int4(0,0,0,0);
    if (i < n) v = *(const int4*)(deg + i);
    int tsum = v.x + v.y + v.z + v.w;
    int x = tsum;
    #pragma unroll
    for (int off = 1; off < 64; off <<= 1){
      int y = __shfl_up(x, off);
      if (l >= off) x += y;
    }
    if (l == 63) wsum[w] = x;
    __syncthreads();
    int woff = 0, tot = 0;
    #pragma unroll
    for (int ww = 0; ww < 16; ++ww){
      int wv = wsum[ww];
      if (ww < w) woff += wv;
      tot += wv;
    }
    int excl = sbase + woff + x - tsum;
    if (i < n){
      int e1 = excl + v.x, e2 = excl + v.x + v.y, e3 = excl + v.x + v.y + v.z;
      row_start[i]   = excl; cursor[i]   = excl;
      row_start[i+1] = e1;   cursor[i+1] = e1;
      row_start[i+2] = e2;   cursor[i+2] = e2;
      row_start[i+3] = e3;   cursor[i+3] = e3;
    }
    __syncthreads();
    if (t == 0) sbase += tot;
    __syncthreads();
  }
  if (t == 0) row_start[n] = sbase;
}

__global__ __launch_bounds__(1024)
void scan2_kernel(const int* __restrict__ degA, int* __restrict__ rsA, int* __restrict__ curA, int nA,
                  const int* __restrict__ degB, int* __restrict__ rsB, int* __restrict__ curB, int nB,
                  float* __restrict__ mvec){
  if (blockIdx.x == 0){
    scan_dev(degA, rsA, curA, nA);
  } else {
    if (threadIdx.x < 144) mvec[threadIdx.x] = 0.f;   // zero mvec for colsum atomics
    scan_dev(degB, rsB, curB, nB);
  }
}

// ---------------------------------------------------------------------------
// k2: CSR scatter (both dirs) || all 4 GAT projection GEMMs merged.
// ---------------------------------------------------------------------------
__global__ __launch_bounds__(256)
void k2_scatter_proj(const int* __restrict__ edst, const int* __restrict__ esrc,
                     int* __restrict__ curA, int* __restrict__ curB,
                     int2* __restrict__ csrA, int2* __restrict__ csrB,
                     const unsigned short* __restrict__ px, const unsigned short* __restrict__ bx,
                     const float* __restrict__ rel_Wl, const float* __restrict__ rel_bl,
                     const float* __restrict__ rel_Wr, const float* __restrict__ rel_br,
                     const float* __restrict__ rev_Wl, const float* __restrict__ rev_bl,
                     const float* __restrict__ rev_Wr, const float* __restrict__ rev_br,
                     unsigned short* __restrict__ xlA, unsigned short* __restrict__ xrA,
                     unsigned short* __restrict__ xlB, unsigned short* __restrict__ xrB,
                     int nbScat, int nbP, int nbB)
{
  __shared__ unsigned short sWt[256*72];   // N=256, KP=72 (>= 64*264 for epilogue)
  int b = blockIdx.x;
  if (b < nbScat){
    int i = b*256 + threadIdx.x;
    if (i < NEDGE){
      int d = edst[i], s = esrc[i];
      int p = atomicAdd(&curA[d], 1);
      csrA[p] = make_int2(i, s);
      int q = atomicAdd(&curB[s], 1);
      csrB[q] = make_int2(i, d);
    }
  } else {
    b -= nbScat;
    if (b < nbP)               mfma_gemm_body<64,16,false,false>(b,            px, rel_Wl, rel_bl, xlA, NP, sWt);
    else if (b < nbP + nbB)    mfma_gemm_body<64,16,false,false>(b-nbP,        bx, rel_Wr, rel_br, xrA, NB, sWt);
    else if (b < nbP + 2*nbB)  mfma_gemm_body<64,16,false,false>(b-nbP-nbB,    bx, rev_Wl, rev_bl, xlB, NB, sWt);
    else                       mfma_gemm_body<64,16,false,false>(b-nbP-2*nbB,  px, rev_Wr, rev_br, xrB, NP, sWt);
  }
}

// ---------------------------------------------------------------------------
// Vectorized column-mean segment (used for ea inside gat2 grid).
// ---------------------------------------------------------------------------
__device__ __forceinline__ void colsum_seg(int bid, int nb, const float4* __restrict__ in4,
                                           long total4, int n4, float* __restrict__ out,
                                           float scale, float* lds){
  int t = threadIdx.x, l = t & 63, w = t >> 6;
  long gid = (long)bid*256 + t;
  long stride = (long)nb*256;
  float4 acc = make_float4(0.f,0.f,0.f,0.f);
  for (long i = gid; i < total4; i += stride){
    float4 v = in4[i];
    acc.x += v.x; acc.y += v.y; acc.z += v.z; acc.w += v.w;
  }
  for (int off = n4; off < 64; off <<= 1){
    acc.x += __shfl_xor(acc.x, off);
    acc.y += __shfl_xor(acc.y, off);
    acc.z += __shfl_xor(acc.z, off);
    acc.w += __shfl_xor(acc.w, off);
  }
  if (l < n4) *(float4*)&lds[(w*n4 + l)*4] = acc;
  __syncthreads();
  if (t < n4*4){
    float sum = lds[t] + lds[n4*4 + t] + lds[2*n4*4 + t] + lds[3*n4*4 + t];
    atomicAdd(&out[t], sum * scale);
  }
  __syncthreads();
}

// ---------------------------------------------------------------------------
// GAT pair-compute (R5-verified math, no online-max). DOT2 / f32 fallback.
// ---------------------------------------------------------------------------
#if HAVE_DOT2
typedef int evt_t;
__device__ __forceinline__ int evload(const float* __restrict__ ea, int e, int l){
  float2 fv = *(const float2*)(ea + (size_t)e*EAD + 2*(l & 7));
  return __builtin_bit_cast(int, __builtin_amdgcn_cvt_pkrtz(fv.x, fv.y));
}
#define GAT_PAIR(X0, X1, EV0, EV1, V1OK, P0MASK)                             \
  {                                                                          \
    float x0 = b2f(X0.x), x1 = b2f(X0.y), x2 = b2f(X0.z), x3 = b2f(X0.w);    \
    float y0 = b2f(X1.x), y1 = b2f(X1.y), y2 = b2f(X1.z), y3 = b2f(X1.w);    \
    float h00 = x0 + r0, h01 = x1 + r1, h02 = x2 + r2, h03 = x3 + r3;        \
    float h10 = y0 + r0, h11 = y1 + r1, h12 = y2 + r2, h13 = y3 + r3;        \
    _Pragma("unroll")                                                        \
    for (int j = 0; j < 8; ++j){                                             \
      int c0 = __builtin_amdgcn_readlane(EV0, j);                            \
      int c1 = __builtin_amdgcn_readlane(EV1, j);                            \
      h16x2 e0 = __builtin_bit_cast(h16x2, c0);                              \
      h16x2 e1 = __builtin_bit_cast(h16x2, c1);                              \
      int4 wr = *(const int4*)&sWeH[j*CW + 4*l];                             \
      h16x2 w0 = __builtin_bit_cast(h16x2, wr.x);                            \
      h16x2 w1 = __builtin_bit_cast(h16x2, wr.y);                            \
      h16x2 w2 = __builtin_bit_cast(h16x2, wr.z);                            \
      h16x2 w3 = __builtin_bit_cast(h16x2, wr.w);                            \
      h00 = __builtin_amdgcn_fdot2(e0, w0, h00, false);                      \
      h01 = __builtin_amdgcn_fdot2(e0, w1, h01, false);                      \
      h02 = __builtin_amdgcn_fdot2(e0, w2, h02, false);                      \
      h03 = __builtin_amdgcn_fdot2(e0, w3, h03, false);                      \
      h10 = __builtin_amdgcn_fdot2(e1, w0, h10, false);                      \
      h11 = __builtin_amdgcn_fdot2(e1, w1, h11, false);                      \
      h12 = __builtin_amdgcn_fdot2(e1, w2, h12, false);                      \
      h13 = __builtin_amdgcn_fdot2(e1, w3, h13, false);                      \
    }                                                                        \
    h00 = fmaxf(h00, 0.2f*h00) * at.x;                                       \
    h01 = fmaxf(h01, 0.2f*h01) * at.y;                                       \
    h02 = fmaxf(h02, 0.2f*h02) * at.z;                                       \
    h03 = fmaxf(h03, 0.2f*h03) * at.w;                                       \
    h10 = fmaxf(h10, 0.2f*h10) * at.x;                                       \
    h11 = fmaxf(h11, 0.2f*h11) * at.y;                                       \
    h12 = fmaxf(h12, 0.2f*h12) * at.z;                                       \
    h13 = fmaxf(h13, 0.2f*h13) * at.w;                                       \
    float g0 = (h00 + h01) + (h02 + h03);                                    \
    float g1 = (h10 + h11) + (h12 + h13);                                    \
    _Pragma("unroll")                                                        \
    for (int off = 1; off < 16; off <<= 1){                                  \
      g0 += __shfl_xor(g0, off);                                             \
      g1 += __shfl_xor(g1, off);                                             \
    }                                                                        \
    float p0 = (P0MASK) ? __expf(g0) : 0.f;                                  \
    float p1 = (V1OK) ? __expf(g1) : 0.f;                                    \
    s += p0 + p1;                                                            \
    a0 = fmaf(p0, x0, fmaf(p1, y0, a0));                                     \
    a1 = fmaf(p0, x1, fmaf(p1, y1, a1));                                     \
    a2 = fmaf(p0, x2, fmaf(p1, y2, a2));                                     \
    a3 = fmaf(p0, x3, fmaf(p1, y3, a3));                                     \
  }
#else
typedef float evt_t;
__device__ __forceinline__ float evload(const float* __restrict__ ea, int e, int l){
  return ea[(size_t)e*EAD + (l & 15)];
}
#define GAT_PAIR(X0, X1, EV0, EV1, V1OK, P0MASK)                             \
  {                                                                          \
    float x0 = b2f(X0.x), x1 = b2f(X0.y), x2 = b2f(X0.z), x3 = b2f(X0.w);    \
    float y0 = b2f(X1.x), y1 = b2f(X1.y), y2 = b2f(X1.z), y3 = b2f(X1.w);    \
    float h00 = x0 + r0, h01 = x1 + r1, h02 = x2 + r2, h03 = x3 + r3;        \
    float h10 = y0 + r0, h11 = y1 + r1, h12 = y2 + r2, h13 = y3 + r3;        \
    int ia0 = __float_as_int(EV0);                                           \
    int ia1 = __float_as_int(EV1);                                           \
    _Pragma("unroll")                                                        \
    for (int k = 0; k < EAD; ++k){                                           \
      float c0 = __int_as_float(__builtin_amdgcn_readlane(ia0, k));          \
      float c1 = __int_as_float(__builtin_amdgcn_readlane(ia1, k));          \
      float4 wv = *(const float4*)&sWeH[k*CW + 4*l];                         \
      h00 = fmaf(c0, wv.x, h00); h01 = fmaf(c0, wv.y, h01);                  \
      h02 = fmaf(c0, wv.z, h02); h03 = fmaf(c0, wv.w, h03);                  \
      h10 = fmaf(c1, wv.x, h10); h11 = fmaf(c1, wv.y, h11);                  \
      h12 = fmaf(c1, wv.z, h12); h13 = fmaf(c1, wv.w, h13);                  \
    }                                                                        \
    h00 = fmaxf(h00, 0.2f*h00) * at.x;                                       \
    h01 = fmaxf(h01, 0.2f*h01) * at.y;                                       \
    h02 = fmaxf(h02, 0.2f*h02) * at.z;                                       \
    h03 = fmaxf(h03, 0.2f*h03) * at.w;                                       \
    h10 = fmaxf(h10, 0.2f*h10) * at.x;                                       \
    h11 = fmaxf(h11, 0.2f*h11) * at.y;                                       \
    h12 = fmaxf(h12, 0.2f*h12) * at.z;                                       \
    h13 = fmaxf(h13, 0.2f*h13) * at.w;                                       \
    float g0 = (h00 + h01) + (h02 + h03);                                    \
    float g1 = (h10 + h11) + (h12 + h13);                                    \
    _Pragma("unroll")                                                        \
    for (int off = 1; off < 16; off <<= 1){                                  \
      g0 += __shfl_xor(g0, off);                                             \
      g1 += __shfl_xor(g1, off);                                             \
    }                                                                        \
    float p0 = (P0MASK) ? __expf(g0) : 0.f;                                  \
    float p1 = (V1OK) ? __expf(g1) : 0.f;                                    \
    s += p0 + p1;                                                            \
    a0 = fmaf(p0, x0, fmaf(p1, y0, a0));                                     \
    a1 = fmaf(p0, x1, fmaf(p1, y1, a1));                                     \
    a2 = fmaf(p0, x2, fmaf(p1, y2, a2));                                     \
    a3 = fmaf(p0, x3, fmaf(p1, y3, a3));                                     \
  }
#endif

// ---------------------------------------------------------------------------
// Merged fused GATv2, BOTH directions + ea colsum + h colsum epilogue.
// R5-proven structure: 2-pair rotation-free double buffer, high occupancy.
// ---------------------------------------------------------------------------
__global__ __launch_bounds__(256)
void gat2_kernel(const unsigned short* __restrict__ xlA_, const unsigned short* __restrict__ xrA_,
                 const float* __restrict__ WeA, const float* __restrict__ attA,
                 const float* __restrict__ biasA, const int2* __restrict__ csrA_,
                 const int* __restrict__ rsA_, float* __restrict__ houtA,
                 const unsigned short* __restrict__ xlB_, const unsigned short* __restrict__ xrB_,
                 const float* __restrict__ WeB, const float* __restrict__ attB,
                 const float* __restrict__ biasB, const int2* __restrict__ csrB_,
                 const int* __restrict__ rsB_, float* __restrict__ houtB,
                 const float* __restrict__ ea, float* __restrict__ mvec, int gsplit)
{
#if HAVE_DOT2
  __shared__ int sWeH[8*CW];     // [kpair][col] packed (We[2k][c], We[2k+1][c])
#else
  __shared__ float sWeH[16*CW];  // f32 We tile
#endif
  __shared__ float csum[4][16][4];
  int t = threadIdx.x, l = t & 63;
  int b = blockIdx.x;
  if (b < NEACOL){
    colsum_seg(b, NEACOL, (const float4*)ea, (long)NEDGE*EAD/4, 4,
               mvec + 128, 1.f/NEDGE, &csum[0][0][0]);
    return;
  }
  b -= NEACOL;
  int ngat = (int)gridDim.x - NEACOL;
  bool isA = b < gsplit;
  const unsigned short* xl = isA ? xlA_ : xlB_;
  const unsigned short* xr = isA ? xrA_ : xrB_;
  const float* We   = isA ? WeA   : WeB;
  const float* att  = isA ? attA  : attB;
  const float* bias = isA ? biasA : biasB;
  const int2* csr   = isA ? csrA_ : csrB_;
  const int* row_start = isA ? rsA_ : rsB_;
  float* hout = isA ? houtA : houtB;
  int ndst = isA ? NB : NP;
  int bid  = isA ? b : b - gsplit;
  int nblk = isA ? gsplit : ngat - gsplit;

#if HAVE_DOT2
  for (int i = t; i < 8*CW; i += 256){
    int j = i >> 8, c = i & 255;
    sWeH[i] = __builtin_bit_cast(int,
        __builtin_amdgcn_cvt_pkrtz(We[(2*j)*CW + c], We[(2*j+1)*CW + c]));
  }
#else
  for (int i = t*4; i < 16*CW; i += 1024)
    *(float4*)&sWeH[i] = *(const float4*)&We[i];
#endif
  __syncthreads();
  float4 at = *(const float4*)&att[4*l];
  float4 bi = *(const float4*)&bias[(l & 15)*4];
  float cs0 = 0.f, cs1 = 0.f, cs2 = 0.f, cs3 = 0.f;   // column-sum of outputs
  int wid = bid*4 + (t >> 6);
  int nw = nblk*4;
  for (int d = wid; d < ndst; d += nw){
    ushort4 ru = *(const ushort4*)(xr + (size_t)d*CW + 4*l);
    float r0 = b2f(ru.x), r1 = b2f(ru.y), r2 = b2f(ru.z), r3 = b2f(ru.w);
    int rs = row_start[d], re = row_start[d+1];
    float s = 0.f;
    float a0 = 0.f, a1 = 0.f, a2 = 0.f, a3 = 0.f;
    if (rs < re){
      int last = re - 1;
      #define CLMP(x) ((x) > last ? last : (x))
      int2 qA0 = csr[rs],         qA1 = csr[CLMP(rs+1)];
      int2 qB0 = csr[CLMP(rs+2)], qB1 = csr[CLMP(rs+3)];
      int2 nA0 = csr[CLMP(rs+4)], nA1 = csr[CLMP(rs+5)];
      int2 nB0 = csr[CLMP(rs+6)], nB1 = csr[CLMP(rs+7)];
      ushort4 xA0 = *(const ushort4*)(xl + (size_t)qA0.y*CW + 4*l);
      ushort4 xA1 = *(const ushort4*)(xl + (size_t)qA1.y*CW + 4*l);
      evt_t  evA0 = evload(ea, qA0.x, l);
      evt_t  evA1 = evload(ea, qA1.x, l);
      ushort4 xB0 = *(const ushort4*)(xl + (size_t)qB0.y*CW + 4*l);
      ushort4 xB1 = *(const ushort4*)(xl + (size_t)qB1.y*CW + 4*l);
      evt_t  evB0 = evload(ea, qB0.x, l);
      evt_t  evB1 = evload(ea, qB1.x, l);
      for (int i = rs; i < re; i += 4){
        int2 mA0 = csr[CLMP(i+8)],  mA1 = csr[CLMP(i+9)];
        int2 mB0 = csr[CLMP(i+10)], mB1 = csr[CLMP(i+11)];
        GAT_PAIR(xA0, xA1, evA0, evA1, (i+1 < re), true);
        xA0 = *(const ushort4*)(xl + (size_t)nA0.y*CW + 4*l);
        xA1 = *(const ushort4*)(xl + (size_t)nA1.y*CW + 4*l);
        evA0 = evload(ea, nA0.x, l);
        evA1 = evload(ea, nA1.x, l);
        nA0 = mA0; nA1 = mA1;
        GAT_PAIR(xB0, xB1, evB0, evB1, (i+3 < re), (i+2 < re));
        xB0 = *(const ushort4*)(xl + (size_t)nB0.y*CW + 4*l);
        xB1 = *(const ushort4*)(xl + (size_t)nB1.y*CW + 4*l);
        evB0 = evload(ea, nB0.x, l);
        evB1 = evload(ea, nB1.x, l);
        nB0 = mB0; nB1 = mB1;
      }
      #undef CLMP
    }
    float inv = 1.f / (s + 1e-16f);
    float v0 = a0*inv, v1 = a1*inv, v2 = a2*inv, v3 = a3*inv;
    v0 += __shfl_xor(v0, 16); v1 += __shfl_xor(v1, 16);
    v2 += __shfl_xor(v2, 16); v3 += __shfl_xor(v3, 16);
    v0 += __shfl_xor(v0, 32); v1 += __shfl_xor(v1, 32);
    v2 += __shfl_xor(v2, 32); v3 += __shfl_xor(v3, 32);
    if (l < 16){
      float4 o;
      o.x = geluf(v0*0.25f + bi.x);
      o.y = geluf(v1*0.25f + bi.y);
      o.z = geluf(v2*0.25f + bi.z);
      o.w = geluf(v3*0.25f + bi.w);
      *(float4*)(hout + (size_t)d*HID + 4*l) = o;
      cs0 += o.x; cs1 += o.y; cs2 += o.z; cs3 += o.w;
    }
  }
  // block-level column-sum reduce -> one atomic per column (64 per block)
  int w = t >> 6;
  if (l < 16){
    csum[w][l][0] = cs0; csum[w][l][1] = cs1;
    csum[w][l][2] = cs2; csum[w][l][3] = cs3;
  }
  __syncthreads();
  if (t < 64){
    int lq = t >> 2, j = t & 3;
    float sum = csum[0][lq][j] + csum[1][lq][j] + csum[2][lq][j] + csum[3][lq][j];
    float scale = isA ? (1.f/NB) : (1.f/NP);
    float* dst = isA ? (mvec + 64) : mvec;
    atomicAdd(&dst[t], sum * scale);
  }
}

// ---------------------------------------------------------------------------
// gemmcat body, 512-thread-safe: per-phase t<256 guards, barriers unguarded.
// tokb = concat(hp,hb,ea)[eids] @ Wet + bet.
// ---------------------------------------------------------------------------
__device__ void gemmcat_body512(int bid, const float* __restrict__ hp, const float* __restrict__ hb,
                                const float* __restrict__ ea, const int* __restrict__ esrc,
                                const int* __restrict__ edst, const int* __restrict__ eids,
                                const float* __restrict__ W, const float* __restrict__ bias,
                                float* __restrict__ out)
{
  __shared__ float sAT[16][68];
  __shared__ float sB[16][68];
  __shared__ int sS[64], sD[64], sE[64];
  int t = threadIdx.x;
  int m0 = (bid >> 1)*64, n0 = (bid & 1)*64;
  if (t < 64){
    int e = eids[m0 + t];
    sS[t] = esrc[e]; sD[t] = edst[e]; sE[t] = e;
  }
  __syncthreads();
  int tr = t >> 4, tc = t & 15;
  float acc[4][4] = {};
  for (int k0 = 0; k0 < 144; k0 += 16){
    if (t < 256){
      int r = t >> 2, c = (t & 3) * 4;
      const float* src; int col = k0 + c;
      if (k0 < 64)       { src = hp + (size_t)sS[r]*HID; }
      else if (k0 < 128) { src = hb + (size_t)sD[r]*HID; col -= 64; }
      else               { src = ea + (size_t)sE[r]*EAD; col -= 128; }
      float4 va = *(const float4*)(src + col);
      sAT[c+0][r] = va.x; sAT[c+1][r] = va.y; sAT[c+2][r] = va.z; sAT[c+3][r] = va.w;
    }
    if (t < 256){
      int r = t >> 4, c = (t & 15) * 4;
      float4 vb = *(const float4*)(W + (size_t)(k0+r)*DD + n0 + c);
      *(float4*)&sB[r][c] = vb;
    }
    __syncthreads();
    if (t < 256){
      #pragma unroll
      for (int k = 0; k < 16; ++k){
        float4 av = *(const float4*)&sAT[k][tr*4];
        float4 bv = *(const float4*)&sB[k][tc*4];
        acc[0][0] = fmaf(av.x, bv.x, acc[0][0]);
        acc[0][1] = fmaf(av.x, bv.y, acc[0][1]);
        acc[0][2] = fmaf(av.x, bv.z, acc[0][2]);
        acc[0][3] = fmaf(av.x, bv.w, acc[0][3]);
        acc[1][0] = fmaf(av.y, bv.x, acc[1][0]);
        acc[1][1] = fmaf(av.y, bv.y, acc[1][1]);
        acc[1][2] = fmaf(av.y, bv.z, acc[1][2]);
        acc[1][3] = fmaf(av.y, bv.w, acc[1][3]);
        acc[2][0] = fmaf(av.z, bv.x, acc[2][0]);
        acc[2][1] = fmaf(av.z, bv.y, acc[2][1]);
        acc[2][2] = fmaf(av.z, bv.z, acc[2][2]);
        acc[2][3] = fmaf(av.z, bv.w, acc[2][3]);
        acc[3][0] = fmaf(av.w, bv.x, acc[3][0]);
        acc[3][1] = fmaf(av.w, bv.y, acc[3][1]);
        acc[3][2] = fmaf(av.w, bv.z, acc[3][2]);
        acc[3][3] = fmaf(av.w, bv.w, acc[3][3]);
      }
    }
    __syncthreads();
  }
  if (t < 256){
    #pragma unroll
    for (int i = 0; i < 4; ++i){
      int gr = m0 + tr*4 + i;
      float4 v;
      v.x = acc[i][0] + bias[n0 + tc*4 + 0];
      v.y = acc[i][1] + bias[n0 + tc*4 + 1];
      v.z = acc[i][2] + bias[n0 + tc*4 + 2];
      v.w = acc[i][3] + bias[n0 + tc*4 + 3];
      *(float4*)(out + (size_t)gr*DD + n0 + tc*4) = v;
    }
  }
}

// ---------------------------------------------------------------------------
// qstageF: one (column-quad q, k-chunk ch) unit of a 6-row GEMM stage.
// ---------------------------------------------------------------------------
template<int K, int N, int NC>
__device__ __forceinline__ void qstageF(const float* __restrict__ x,
                                        const float* __restrict__ W,
                                        float (&a)[6][4], int q, int ch)
{
  constexpr int NQ = N/4;
  constexpr int KC = K/NC;     // multiple of 4
  constexpr int J  = KC/4;     // power of 2
  const float4* wp = (const float4*)W + (size_t)(ch*KC)*NQ + q;
  const float* xb = x + ch*KC;
  float4 wv[KC];
  int kx[J];
  #pragma unroll
  for (int j = 0; j < J; ++j){
    int k4 = (j + ch) & (J-1);
    kx[j] = k4;
    wv[j*4+0] = wp[(size_t)(k4*4+0)*NQ];
    wv[j*4+1] = wp[(size_t)(k4*4+1)*NQ];
    wv[j*4+2] = wp[(size_t)(k4*4+2)*NQ];
    wv[j*4+3] = wp[(size_t)(k4*4+3)*NQ];
  }
  #pragma unroll
  for (int s = 0; s < 6; ++s){ a[s][0]=0.f; a[s][1]=0.f; a[s][2]=0.f; a[s][3]=0.f; }
  #pragma unroll
  for (int j = 0; j < J; ++j){
    #pragma unroll
    for (int s = 0; s < 6; ++s){
      float4 xv = *(const float4*)&xb[s*K + kx[j]*4];
      a[s][0]=fmaf(xv.x,wv[j*4+0].x,a[s][0]); a[s][0]=fmaf(xv.y,wv[j*4+1].x,a[s][0]);
      a[s][0]=fmaf(xv.z,wv[j*4+2].x,a[s][0]); a[s][0]=fmaf(xv.w,wv[j*4+3].x,a[s][0]);
      a[s][1]=fmaf(xv.x,wv[j*4+0].y,a[s][1]); a[s][1]=fmaf(xv.y,wv[j*4+1].y,a[s][1]);
      a[s][1]=fmaf(xv.z,wv[j*4+2].y,a[s][1]); a[s][1]=fmaf(xv.w,wv[j*4+3].y,a[s][1]);
      a[s][2]=fmaf(xv.x,wv[j*4+0].z,a[s][2]); a[s][2]=fmaf(xv.y,wv[j*4+1].z,a[s][2]);
      a[s][2]=fmaf(xv.z,wv[j*4+2].z,a[s][2]); a[s][2]=fmaf(xv.w,wv[j*4+3].z,a[s][2]);
      a[s][3]=fmaf(xv.x,wv[j*4+0].w,a[s][3]); a[s][3]=fmaf(xv.y,wv[j*4+1].w,a[s][3]);
      a[s][3]=fmaf(xv.z,wv[j*4+2].w,a[s][3]); a[s][3]=fmaf(xv.w,wv[j*4+3].w,a[s][3]);
    }
  }
  #pragma unroll
  for (int off = 1; off < NC; off <<= 1){
    #pragma unroll
    for (int s = 0; s < 6; ++s){
      a[s][0]+=__shfl_xor(a[s][0],off); a[s][1]+=__shfl_xor(a[s][1],off);
      a[s][2]+=__shfl_xor(a[s][2],off); a[s][3]+=__shfl_xor(a[s][3],off);
    }
  }
}

// ---------------------------------------------------------------------------
// xform body (512 threads, verbatim R11): buildx + 2 encoder layers + ctxdot.
// ---------------------------------------------------------------------------
__device__ void xform_body(const float* __restrict__ hist, const float* __restrict__ mvec,
                           const float* __restrict__ Wgs, const float* __restrict__ bgs,
                           const float* __restrict__ pos,
                           const float* __restrict__ Wqkv, const float* __restrict__ bqkv,
                           const float* __restrict__ Wo, const float* __restrict__ bo,
                           const float* __restrict__ ln1g, const float* __restrict__ ln1b,
                           const float* __restrict__ W1, const float* __restrict__ b1,
                           const float* __restrict__ W2, const float* __restrict__ b2,
                           const float* __restrict__ ln2g, const float* __restrict__ ln2b,
                           const float* __restrict__ Wc1, const float* __restrict__ bc1,
                           float* __restrict__ bias2)
{
  __shared__ float sx[SEQ*DD];       // current x
  __shared__ float sq[SEQ*3*DD];     // qkv
  __shared__ float sh[SEQ*512];      // ffn hidden / pre-LN1 buffer
  __shared__ float st[SEQ*DD];       // attn-out / pre-LN2 buffer
  __shared__ float sc[4][6][6];
  __shared__ float smv[144];
  int t = threadIdx.x;

  // rows 0..4 = hist+pos ; mvec -> LDS
  for (int i = t; i < (SEQ-1)*DD; i += 512) sx[i] = hist[i] + pos[i];
  if (t < 144) smv[t] = mvec[t];
  __syncthreads();
  // row 5 = mvec @ Wgs + bgs + pos[5]   (32 quads x 8 chunks of 18 k)
  if (t < 256){
    int q = t >> 3, ch = t & 7;
    float4 wv[18];
    #pragma unroll
    for (int kk = 0; kk < 18; ++kk)
      wv[kk] = *(const float4*)&Wgs[(ch*18+kk)*DD + q*4];
    float a0=0.f,a1=0.f,a2=0.f,a3=0.f;
    #pragma unroll
    for (int kk = 0; kk < 18; ++kk){
      float xv = smv[ch*18+kk];
      a0=fmaf(xv,wv[kk].x,a0); a1=fmaf(xv,wv[kk].y,a1);
      a2=fmaf(xv,wv[kk].z,a2); a3=fmaf(xv,wv[kk].w,a3);
    }
    #pragma unroll
    for (int off = 1; off < 8; off <<= 1){
      a0+=__shfl_xor(a0,off); a1+=__shfl_xor(a1,off);
      a2+=__shfl_xor(a2,off); a3+=__shfl_xor(a3,off);
    }
    if (ch == 0){
      int n = q*4, base = (SEQ-1)*DD + n;
      sx[base+0]=a0+bgs[n+0]+pos[base+0];
      sx[base+1]=a1+bgs[n+1]+pos[base+1];
      sx[base+2]=a2+bgs[n+2]+pos[base+2];
      sx[base+3]=a3+bgs[n+3]+pos[base+3];
    }
  }
  __syncthreads();

  for (int lyr = 0; lyr < L; ++lyr){
    // qkv = x @ Wqkv + bqkv   (96 quads x NC=4 chunks = 384 units, 32 loads ea)
    if (t < 384){
      int q = t >> 2, ch = t & 3;
      const float* wq = Wqkv + (size_t)lyr*DD*3*DD;
      const float* bq = bqkv + lyr*3*DD;
      float a[6][4];
      qstageF<128,384,4>(sx, wq, a, q, ch);
      if (ch == 0){
        int n = q*4;
        #pragma unroll
        for (int s = 0; s < 6; ++s){
          sq[s*384+n+0]=a[s][0]+bq[n+0];
          sq[s*384+n+1]=a[s][1]+bq[n+1];
          sq[s*384+n+2]=a[s][2]+bq[n+2];
          sq[s*384+n+3]=a[s][3]+bq[n+3];
        }
      }
    }
    __syncthreads();
    // scores
    if (t < 144){
      int h = t/36, r = t%36, qi = r/6, ki = r%6;
      float acc = 0.f;
      #pragma unroll
      for (int d2 = 0; d2 < 32; ++d2)
        acc = fmaf(sq[qi*384 + h*32 + d2], sq[ki*384 + 128 + h*32 + d2], acc);
      sc[h][qi][ki] = acc * 0.17677669529663687f;
    }
    __syncthreads();
    if (t < 24){
      int h = t/6, qi = t%6;
      float* row = sc[h][qi];
      float mx = row[0];
      #pragma unroll
      for (int k = 1; k < 6; ++k) mx = fmaxf(mx, row[k]);
      float sm = 0.f;
      #pragma unroll
      for (int k = 0; k < 6; ++k){ row[k] = __expf(row[k]-mx); sm += row[k]; }
      float inv = 1.f/sm;
      #pragma unroll
      for (int k = 0; k < 6; ++k) row[k] *= inv;
    }
    __syncthreads();
    // attention output -> st
    for (int i = t; i < SEQ*DD; i += 512){
      int s = i >> 7, n = i & 127, h = n >> 5, d2 = n & 31;
      float acc = 0.f;
      #pragma unroll
      for (int ki = 0; ki < 6; ++ki)
        acc = fmaf(sc[h][s][ki], sq[ki*384 + 256 + h*32 + d2], acc);
      st[i] = acc;
    }
    __syncthreads();
    // proj: st @ Wo + bo + resid(sx) -> sh   (32 quads x NC=16 = 512 units, 8 loads)
    {
      int q = t >> 4, ch = t & 15;
      float a[6][4];
      qstageF<128,128,16>(st, Wo + (size_t)lyr*DD*DD, a, q, ch);
      if (ch == 0){
        int n = q*4;
        const float* bop = bo + lyr*DD;
        #pragma unroll
        for (int s = 0; s < 6; ++s){
          sh[s*128+n+0]=a[s][0]+bop[n+0]+sx[s*128+n+0];
          sh[s*128+n+1]=a[s][1]+bop[n+1]+sx[s*128+n+1];
          sh[s*128+n+2]=a[s][2]+bop[n+2]+sx[s*128+n+2];
          sh[s*128+n+3]=a[s][3]+bop[n+3]+sx[s*128+n+3];
        }
      }
    }
    __syncthreads();
    // LN1 (single phase): sh -> sx, one wave per row
    {
      int w = t >> 6, lw = t & 63;
      if (w < SEQ){
        const float* g = ln1g + lyr*DD; const float* be = ln1b + lyr*DD;
        float v0 = sh[w*DD + lw], v1 = sh[w*DD + 64 + lw];
        float sm = v0 + v1;
        #pragma unroll
        for (int off = 1; off < 64; off <<= 1) sm += __shfl_xor(sm, off);
        float mean = sm * 0.0078125f;
        float d0 = v0-mean, d1 = v1-mean;
        float qv = d0*d0 + d1*d1;
        #pragma unroll
        for (int off = 1; off < 64; off <<= 1) qv += __shfl_xor(qv, off);
        float inv = rsqrtf(qv*0.0078125f + 1e-5f);
        sx[w*DD + lw]      = d0*inv*g[lw] + be[lw];
        sx[w*DD + 64 + lw] = d1*inv*g[64+lw] + be[64+lw];
      }
    }
    __syncthreads();
    // ffn1: sx @ W1 -> gelu -> sh[6][512]   (128 quads x NC=4 = 512 units, 32 loads)
    {
      int q = t >> 2, ch = t & 3;
      const float* w1 = W1 + (size_t)lyr*DD*512;
      const float* b1p = b1 + lyr*512;
      float a[6][4];
      qstageF<128,512,4>(sx, w1, a, q, ch);
      if (ch == 0){
        int n = q*4;
        #pragma unroll
        for (int s = 0; s < 6; ++s){
          sh[s*512+n+0]=geluf(a[s][0]+b1p[n+0]);
          sh[s*512+n+1]=geluf(a[s][1]+b1p[n+1]);
          sh[s*512+n+2]=geluf(a[s][2]+b1p[n+2]);
          sh[s*512+n+3]=geluf(a[s][3]+b1p[n+3]);
        }
      }
    }
    __syncthreads();
    // ffn2: sh @ W2 + b2 + resid(sx) -> st   (32 quads x NC=16 = 512 units, 32 loads)
    {
      int q = t >> 4, ch = t & 15;
      const float* w2 = W2 + (size_t)lyr*512*DD;
      const float* b2p = b2 + lyr*DD;
      float a[6][4];
      qstageF<512,128,16>(sh, w2, a, q, ch);
      if (ch == 0){
        int n = q*4;
        #pragma unroll
        for (int s = 0; s < 6; ++s){
          st[s*128+n+0]=a[s][0]+b2p[n+0]+sx[s*128+n+0];
          st[s*128+n+1]=a[s][1]+b2p[n+1]+sx[s*128+n+1];
          st[s*128+n+2]=a[s][2]+b2p[n+2]+sx[s*128+n+2];
          st[s*128+n+3]=a[s][3]+b2p[n+3]+sx[s*128+n+3];
        }
      }
    }
    __syncthreads();
    // LN2 (single phase): st -> sx
    {
      int w = t >> 6, lw = t & 63;
      if (w < SEQ){
        const float* g = ln2g + lyr*DD; const float* be = ln2b + lyr*DD;
        float v0 = st[w*DD + lw], v1 = st[w*DD + 64 + lw];
        float sm = v0 + v1;
        #pragma unroll
        for (int off = 1; off < 64; off <<= 1) sm += __shfl_xor(sm, off);
        float mean = sm * 0.0078125f;
        float d0 = v0-mean, d1 = v1-mean;
        float qv = d0*d0 + d1*d1;
        #pragma unroll
        for (int off = 1; off < 64; off <<= 1) qv += __shfl_xor(qv, off);
        float inv = rsqrtf(qv*0.0078125f + 1e-5f);
        sx[w*DD + lw]      = d0*inv*g[lw] + be[lw];
        sx[w*DD + 64 + lw] = d1*inv*g[64+lw] + be[64+lw];
      }
    }
    __syncthreads();
  }
  // ctxdot: bias2[n] = bc1[n] + sum_k ctx[k]*Wc1[128+k][n]  (32 quads x 8 chunks)
  if (t < 256){
    int q = t >> 3, ch = t & 7;
    const float4* wp = (const float4*)(Wc1 + (size_t)DD*DD) + (size_t)(ch*16)*32 + q;
    const float* xb = &sx[(SEQ-1)*DD + ch*16];
    float4 wv[16];
    int kx[4];
    #pragma unroll
    for (int j = 0; j < 4; ++j){
      int k4 = (j + ch) & 3;
      kx[j] = k4;
      wv[j*4+0] = wp[(size_t)(k4*4+0)*32];
      wv[j*4+1] = wp[(size_t)(k4*4+1)*32];
      wv[j*4+2] = wp[(size_t)(k4*4+2)*32];
      wv[j*4+3] = wp[(size_t)(k4*4+3)*32];
    }
    float a0=0.f,a1=0.f,a2=0.f,a3=0.f;
    #pragma unroll
    for (int j = 0; j < 4; ++j){
      float4 xv = *(const float4*)&xb[kx[j]*4];
      a0=fmaf(xv.x,wv[j*4+0].x,a0); a0=fmaf(xv.y,wv[j*4+1].x,a0);
      a0=fmaf(xv.z,wv[j*4+2].x,a0); a0=fmaf(xv.w,wv[j*4+3].x,a0);
      a1=fmaf(xv.x,wv[j*4+0].y,a1); a1=fmaf(xv.y,wv[j*4+1].y,a1);
      a1=fmaf(xv.z,wv[j*4+2].y,a1); a1=fmaf(xv.w,wv[j*4+3].y,a1);
      a2=fmaf(xv.x,wv[j*4+0].z,a2); a2=fmaf(xv.y,wv[j*4+1].z,a2);
      a2=fmaf(xv.z,wv[j*4+2].z,a2); a2=fmaf(xv.w,wv[j*4+3].z,a2);
      a3=fmaf(xv.x,wv[j*4+0].w,a3); a3=fmaf(xv.y,wv[j*4+1].w,a3);
      a3=fmaf(xv.z,wv[j*4+2].w,a3); a3=fmaf(xv.w,wv[j*4+3].w,a3);
    }
    #pragma unroll
    for (int off = 1; off < 8; off <<= 1){
      a0+=__shfl_xor(a0,off); a1+=__shfl_xor(a1,off);
      a2+=__shfl_xor(a2,off); a3+=__shfl_xor(a3,off);
    }
    if (ch == 0){
      int n = q*4;
      bias2[n+0]=a0+bc1[n+0];
      bias2[n+1]=a1+bc1[n+1];
      bias2[n+2]=a2+bc1[n+2];
      bias2[n+3]=a3+bc1[n+3];
    }
  }
}

// ---------------------------------------------------------------------------
// k3: gemmcat (blocks 0..255, 512 threads w/ t<256 active) || xform (block 256).
// Both depend only on gat2 outputs; merging hides gemmcat under xform.
// ---------------------------------------------------------------------------
__global__ __launch_bounds__(512)
void k3_gemmcat_xform(const float* __restrict__ hp, const float* __restrict__ hb,
                      const float* __restrict__ ea, const int* __restrict__ esrc,
                      const int* __restrict__ edst, const int* __restrict__ eids,
                      const float* __restrict__ Wet, const float* __restrict__ bet,
                      float* __restrict__ tokb,
                      const float* __restrict__ hist, const float* __restrict__ mvec,
                      const float* __restrict__ Wgs, const float* __restrict__ bgs,
                      const float* __restrict__ pos,
                      const float* __restrict__ Wqkv, const float* __restrict__ bqkv,
                      const float* __restrict__ Wo, const float* __restrict__ bo,
                      const float* __restrict__ ln1g, const float* __restrict__ ln1b,
                      const float* __restrict__ W1, const float* __restrict__ b1,
                      const float* __restrict__ W2, const float* __restrict__ b2,
                      const float* __restrict__ ln2g, const float* __restrict__ ln2b,
                      const float* __restrict__ Wc1, const float* __restrict__ bc1,
                      float* __restrict__ bias2)
{
  if (blockIdx.x < 256){
    gemmcat_body512(blockIdx.x, hp, hb, ea, esrc, edst, eids, Wet, bet, tokb);
  } else {
    xform_body(hist, mvec, Wgs, bgs, pos, Wqkv, bqkv, Wo, bo, ln1g, ln1b,
               W1, b1, W2, b2, ln2g, ln2b, Wc1, bc1, bias2);
  }
}

// ---------------------------------------------------------------------------
// cls: fused hid = gelu(tokb @ Wc1[0:128] + bias2) ; out = hid @ Wc2 + bc2.
// ---------------------------------------------------------------------------
__global__ __launch_bounds__(256)
void cls_kernel(const float* __restrict__ A, const float* __restrict__ W,
                const float* __restrict__ bias2, const float* __restrict__ Wc2,
                const float* __restrict__ bc2, float* __restrict__ out)
{
  __shared__ float sAT[16][68];
  __shared__ float sB[16][132];
  __shared__ float sH[64][129];
  int t = threadIdx.x;
  int m0 = blockIdx.x * 64;
  int tr = t >> 4, tc = t & 15;
  float acc[4][8] = {};
  for (int k0 = 0; k0 < DD; k0 += 16){
    {
      int r = t >> 2, c = (t & 3) * 4;
      float4 va = *(const float4*)(A + (size_t)(m0+r)*DD + k0 + c);
      sAT[c+0][r] = va.x; sAT[c+1][r] = va.y; sAT[c+2][r] = va.z; sAT[c+3][r] = va.w;
    }
    {
      int r = t >> 4, c = (t & 15) * 8;
      float4 b0 = *(const float4*)(W + (size_t)(k0+r)*DD + c);
      float4 b1 = *(const float4*)(W + (size_t)(k0+r)*DD + c + 4);
      *(float4*)&sB[r][c] = b0;
      *(float4*)&sB[r][c+4] = b1;
    }
    __syncthreads();
    #pragma unroll
    for (int k = 0; k < 16; ++k){
      float4 av = *(const float4*)&sAT[k][tr*4];
      float4 b0 = *(const float4*)&sB[k][tc*8];
      float4 b1 = *(const float4*)&sB[k][tc*8+4];
      #pragma unroll
      for (int i = 0; i < 4; ++i){
        float avi = (i==0)?av.x:(i==1)?av.y:(i==2)?av.z:av.w;
        acc[i][0] = fmaf(avi, b0.x, acc[i][0]);
        acc[i][1] = fmaf(avi, b0.y, acc[i][1]);
        acc[i][2] = fmaf(avi, b0.z, acc[i][2]);
        acc[i][3] = fmaf(avi, b0.w, acc[i][3]);
        acc[i][4] = fmaf(avi, b1.x, acc[i][4]);
        acc[i][5] = fmaf(avi, b1.y, acc[i][5]);
        acc[i][6] = fmaf(avi, b1.z, acc[i][6]);
        acc[i][7] = fmaf(avi, b1.w, acc[i][7]);
      }
    }
    __syncthreads();
  }
  // epilogue: gelu(acc + bias2) -> sH
  #pragma unroll
  for (int i = 0; i < 4; ++i){
    #pragma unroll
    for (int j = 0; j < 8; ++j){
      sH[tr*4+i][tc*8+j] = geluf(acc[i][j] + bias2[tc*8+j]);
    }
  }
  __syncthreads();
  // head: out[m0+row][c] = sH[row] . Wc2[:,c] + bc2[c]
  if (t < 64){
    float a10[NCLS];
    #pragma unroll
    for (int c = 0; c < NCLS; ++c) a10[c] = bc2[c];
    for (int k = 0; k < DD; ++k){
      float hv = sH[t][k];
      #pragma unroll
      for (int c = 0; c < NCLS; ++c)
        a10[c] = fmaf(hv, Wc2[k*NCLS + c], a10[c]);
    }
    #pragma unroll
    for (int c = 0; c < NCLS; ++c)
      out[(size_t)(m0+t)*NCLS + c] = a10[c];
  }
}

extern "C" void kernel_launch(void* const* d_in, const int* in_sizes, int n_in,
                              void* d_out, int out_size, void* d_ws, size_t ws_size,
                              hipStream_t stream){
  (void)in_sizes; (void)n_in; (void)out_size; (void)ws_size;
  const float* pitcher = (const float*)d_in[0];
  const float* batter  = (const float*)d_in[1];
  const float* eattr   = (const float*)d_in[2];
  const float* hist    = (const float*)d_in[3];
  const float* Wp = (const float*)d_in[4];
  const float* bp = (const float*)d_in[5];
  const float* Wb = (const float*)d_in[6];
  const float* bb = (const float*)d_in[7];
  const float* rel_Wl  = (const float*)d_in[8];
  const float* rel_bl  = (const float*)d_in[9];
  const float* rel_Wr  = (const float*)d_in[10];
  const float* rel_br  = (const float*)d_in[11];
  const float* rel_We  = (const float*)d_in[12];
  const float* rel_att = (const float*)d_in[13];
  const float* rel_bias= (const float*)d_in[14];
  const float* rev_Wl  = (const float*)d_in[15];
  const float* rev_bl  = (const float*)d_in[16];
  const float* rev_Wr  = (const float*)d_in[17];
  const float* rev_br  = (const float*)d_in[18];
  const float* rev_We  = (const float*)d_in[19];
  const float* rev_att = (const float*)d_in[20];
  const float* rev_bias= (const float*)d_in[21];
  const float* Wgs = (const float*)d_in[22];
  const float* bgs = (const float*)d_in[23];
  const float* Wet = (const float*)d_in[24];
  const float* bet = (const float*)d_in[25];
  const float* pos = (const float*)d_in[26];
  const float* Wqkv= (const float*)d_in[27];
  const float* bqkv= (const float*)d_in[28];
  const float* Wo  = (const float*)d_in[29];
  const float* bo  = (const float*)d_in[30];
  const float* ln1g= (const float*)d_in[31];
  const float* ln1b= (const float*)d_in[32];
  const float* W1  = (const float*)d_in[33];
  const float* b1  = (const float*)d_in[34];
  const float* W2  = (const float*)d_in[35];
  const float* b2  = (const float*)d_in[36];
  const float* ln2g= (const float*)d_in[37];
  const float* ln2b= (const float*)d_in[38];
  const float* Wc1 = (const float*)d_in[39];
  const float* bc1 = (const float*)d_in[40];
  const float* Wc2 = (const float*)d_in[41];
  const float* bc2 = (const float*)d_in[42];
  const int* esrc = (const int*)d_in[43];
  const int* edst = (const int*)d_in[44];
  const int* eids = (const int*)d_in[45];

  // workspace carve-out
  char* w = (char*)d_ws;
  size_t off = 0;
  auto alloc = [&](size_t bytes)->void*{
    void* p = (void*)(w + off);
    off += (bytes + 255) & ~(size_t)255;
    return p;
  };
  unsigned short* px_bf  = (unsigned short*)alloc((size_t)NP*HID*2);
  unsigned short* bx_bf  = (unsigned short*)alloc((size_t)NB*HID*2);
  float*          hp     = (float*)alloc((size_t)NP*HID*4);
  float*          hb     = (float*)alloc((size_t)NB*HID*4);
  unsigned short* xlA    = (unsigned short*)alloc((size_t)NP*CW*2);  // rel: src=pitcher
  unsigned short* xrA    = (unsigned short*)alloc((size_t)NB*CW*2);  // rel: dst=batter
  unsigned short* xlB    = (unsigned short*)alloc((size_t)NB*CW*2);  // rev: src=batter
  unsigned short* xrB    = (unsigned short*)alloc((size_t)NP*CW*2);  // rev: dst=pitcher
  int*            degAB  = (int*)alloc((size_t)(NB+NP)*4);
  int*            degA   = degAB;
  int*            degB   = degAB + NB;
  int*            rowstA = (int*)alloc((size_t)(NB+1)*4);
  int*            rowstB = (int*)alloc((size_t)(NP+1)*4);
  int*            cursA  = (int*)alloc((size_t)NB*4);
  int*            cursB  = (int*)alloc((size_t)NP*4);
  int2*           csrA   = (int2*)alloc((size_t)NEDGE*8);
  int2*           csrB   = (int2*)alloc((size_t)NEDGE*8);
  float*          mvec   = (float*)alloc(144*4);
  float*          bias2  = (float*)alloc(DD*4);
  // alias over dead GAT buffer (xlA dead after gat2):
  float*          tokb   = (float*)xlA;   // BEDGE*DD*4 = 4.19MB <= 5.12MB

  const int nbCount = (NEDGE + 255)/256;          // 1172
  const int nbP = (NP + 63)/64;                   // 157
  const int nbB = (NB + 63)/64;                   // 469

  // k1: degree count (both dirs) || node encoders
  hipMemsetAsync(degAB, 0, (size_t)(NB+NP)*4, stream);
  k1_count_enc<<<nbCount + nbP + nbB, 256, 0, stream>>>(
      edst, esrc, degA, degB,
      pitcher, Wp, bp, px_bf, batter, Wb, bb, bx_bf, nbCount, nbP);

  // scan both CSRs (2 blocks) + zero mvec
  scan2_kernel<<<2, 1024, 0, stream>>>(degA, rowstA, cursA, NB,
                                       degB, rowstB, cursB, NP, mvec);

  // k2: CSR scatter || all four projection GEMMs
  k2_scatter_proj<<<nbCount + 2*nbP + 2*nbB, 256, 0, stream>>>(
      edst, esrc, cursA, cursB, csrA, csrB, px_bf, bx_bf,
      rel_Wl, rel_bl, rel_Wr, rel_br, rev_Wl, rev_bl, rev_Wr, rev_br,
      xlA, xrA, xlB, xrB, nbCount, nbP, nbB);

  // merged GAT (both dirs) + ea colsum + h colsum epilogue
  gat2_kernel<<<NEACOL + 4096, 256, 0, stream>>>(
      xlA, xrA, rel_We, rel_att, rel_bias, csrA, rowstA, hb,
      xlB, xrB, rev_We, rev_att, rev_bias, csrB, rowstB, hp,
      eattr, mvec, 2048);

  // k3: token-gather GEMM (blocks 0..255) || fused transformer (block 256)
  k3_gemmcat_xform<<<257, 512, 0, stream>>>(
      hp, hb, eattr, esrc, edst, eids, Wet, bet, tokb,
      hist, mvec, Wgs, bgs, pos, Wqkv, bqkv, Wo, bo, ln1g, ln1b,
      W1, b1, W2, b2, ln2g, ln2b, Wc1, bc1, bias2);

  // classifier (hid GEMM + head fused)
  cls_kernel<<<BEDGE/64, 256, 0, stream>>>(tokb, Wc1, bias2, Wc2, bc2, (float*)d_out);
}